// Round 6
// baseline (41047.543 us; speedup 1.0000x reference)
//
#include <hip/hip_runtime.h>

#define NB 128
#define NT 1024
#define TT 1024
#define DI 64
#define DH 512
#define DB 128
#define GZ 2048
#define KZ 576

typedef unsigned short u16;
typedef unsigned int u32;
typedef unsigned long long u64;

#if defined(__has_builtin)
#if __has_builtin(__builtin_amdgcn_fdot2)
#define HAS_FDOT2 1
#endif
#endif

typedef _Float16 half2v __attribute__((ext_vector_type(2)));

__device__ __forceinline__ float bf2f(u16 u) {
  union { u32 i; float f; } v; v.i = ((u32)u) << 16; return v.f;
}
__device__ __forceinline__ u16 f2bf_rne(float x) {
  union { float f; u32 i; } v; v.f = x;
  return (u16)((v.i + 0x7fffu + ((v.i >> 16) & 1u)) >> 16);
}
__device__ __forceinline__ float fsig(float x) {
  return __builtin_amdgcn_rcpf(1.f + __expf(-x));
}
__device__ __forceinline__ float ftanh(float x) {
  return 1.f - 2.f * __builtin_amdgcn_rcpf(__expf(2.f * x) + 1.f);
}
__device__ __forceinline__ float dot2p(u32 w, u32 a, float acc) {
#ifdef HAS_FDOT2
  return __builtin_amdgcn_fdot2(__builtin_bit_cast(half2v, w),
                                __builtin_bit_cast(half2v, a), acc, false);
#else
  half2v hw = __builtin_bit_cast(half2v, w), ha = __builtin_bit_cast(half2v, a);
  acc = fmaf((float)hw.x, (float)ha.x, acc);
  return fmaf((float)hw.y, (float)ha.y, acc);
#endif
}
__device__ __forceinline__ u32 packf16(float x, float y) {
  half2v h; h.x = (_Float16)x; h.y = (_Float16)y;
  return __builtin_bit_cast(u32, h);
}

// ---- ws layout (bytes, 256-aligned). x is read straight from d_in now. ----
#define O_WZP  256
#define O_BBP  (O_WZP + 2359296)      // wz pairs: 288*2048 u32
#define O_FFP  (O_BBP + 147456)       // bb pairs: 288*128 u32
#define O_BIF  (O_FFP + 524288)       // ff pairs: 4*64*512 u32
#define O_FFB  (O_BIF + 8192)         // bi f32[2048]
#define O_BBBF (O_FFB + 8192)         // ffb f32[4*512]
#define O_HWP  (O_BBBF + 512)         // bbb f32[128]
#define O_HBF  (O_HWP + 2048)         // hw pairs u32[512]
#define O_HL   (O_HBF + 256)          // h_lstm exchange: 64*2*2*256 u32
#define O_HN   (O_HL + 262144)        // h_new exchange
#define O_FLG  (O_HN + 262144)        // flags: 64*2*2*2 u32
#define WS_NEED ((u64)(O_FLG + 2048)) // ~3.58 MB

// ---------------- dtype detection (validated rounds 3-5) ----------------
__global__ void detect_kernel(const u16* x, const u16* wi, const u16* wh, int* flag) {
  const int l = threadIdx.x;
  int cnt = (((x[2 * l] >> 7) & 0xFF) < 134)
          + (((wi[2 * l] >> 7) & 0xFF) < 134)
          + (((wh[2 * l] >> 7) & 0xFF) < 134);
#pragma unroll
  for (int off = 32; off > 0; off >>= 1) cnt += __shfl_down(cnt, off, 64);
  if (l == 0) *flag = (cnt >= 180) ? 1 : 0;  // 1 = bf16 inputs
}

__device__ __forceinline__ float ldf(int f, const void* s, u32 i) {
  return f ? bf2f(((const u16*)s)[i]) : ((const float*)s)[i];
}

// ---- prep kernels (layouts validated in round 5) ----
__global__ void pwz_kernel(const void* Wi, const void* Wh,
                           const int* __restrict__ flag, u32* __restrict__ wzp) {
  const int o = blockIdx.x * 256 + threadIdx.x;
  const int k2 = blockIdx.y;
  const int f = *flag;
  float a, b;
  if (k2 < 32) {
    const u32 i = (u32)o * DI + 2 * k2;
    a = ldf(f, Wi, i); b = ldf(f, Wi, i + 1);
  } else {
    const u32 i = (u32)o * DH + 2 * (k2 - 32);
    a = ldf(f, Wh, i); b = ldf(f, Wh, i + 1);
  }
  wzp[(u32)k2 * GZ + o] = packf16(a, b);
}
__global__ void pbb_kernel(const void* bb, const int* __restrict__ flag,
                           u32* __restrict__ bbp) {
  const int m = threadIdx.x;
  const int k2 = blockIdx.x;
  const int f = *flag;
  const u32 i = (u32)m * KZ + 2 * k2;
  bbp[(u32)k2 * DB + m] = packf16(ldf(f, bb, i), ldf(f, bb, i + 1));
}
__global__ void pff_kernel(const void* f1, const void* f2, const void* ta,
                           const void* tb, const int* __restrict__ flag,
                           u32* __restrict__ ffp) {
  const int o = blockIdx.x * 256 + threadIdx.x;
  const int k2 = blockIdx.y;
  const int mat = blockIdx.z;
  const void* s = (mat == 0) ? f1 : (mat == 1) ? f2 : (mat == 2) ? ta : tb;
  const int f = *flag;
  const u32 i = (u32)o * DB + 2 * k2;
  ffp[((u32)mat * 64 + k2) * DH + o] = packf16(ldf(f, s, i), ldf(f, s, i + 1));
}
__global__ void psmall_kernel(const void* bi_s, const void* f1b_s, const void* f2b_s,
                              const void* tab_s, const void* tbb_s, const void* bbb_s,
                              const void* hw_s, const void* hb_s,
                              const int* __restrict__ flag,
                              float* __restrict__ bif, float* __restrict__ ffb,
                              float* __restrict__ bbbf, u32* __restrict__ hwp,
                              float* __restrict__ hbf) {
  const int f = *flag;
  for (int i = threadIdx.x; i < 2048; i += 1024) {
    bif[i] = ldf(f, bi_s, i);
    if (i < 512) {
      ffb[i]        = ldf(f, f1b_s, i);
      ffb[512 + i]  = ldf(f, f2b_s, i);
      ffb[1024 + i] = ldf(f, tab_s, i);
      ffb[1536 + i] = ldf(f, tbb_s, i);
      const int w = i >> 8, pr = i & 255;
      hwp[i] = packf16(ldf(f, hw_s, w * DH + 2 * pr), ldf(f, hw_s, w * DH + 2 * pr + 1));
    }
    if (i < 128) bbbf[i] = ldf(f, bbb_s, i);
    if (i < 2)   hbf[i] = ldf(f, hb_s, i);
  }
}

// ------------- main scan: 64 pairs x 2 halves, 2 batch rows per block -------------
// block = (pair pb, half g). Owns h-units [g*256,(g+1)*256) for rows {2pb, 2pb+1}.
// Per-step weight stream: 1.18MB (Wz half) + 0.147MB (bb, duplicated) + 0.26MB (ff half)
// amortized over 2 rows. Halves exchange h_lstm / h_new (256 u32) twice per step via
// agent-scope atomics with step-tagged flags (exact-match; poison/replay safe).
__global__ __launch_bounds__(NT)
void scan_pair(const void* __restrict__ xraw, const int* __restrict__ flagp,
               const u32* __restrict__ wzp, const u32* __restrict__ bbp,
               const u32* __restrict__ ffp,
               const float* __restrict__ bif, const float* __restrict__ ffbv,
               const float* __restrict__ bbbf, const u32* __restrict__ hwp,
               const float* __restrict__ hbf,
               u32* __restrict__ HL, u32* __restrict__ HN, u32* __restrict__ FLG,
               float* __restrict__ out)
{
  __shared__ __align__(16) u32   zin2u[2 * 288];   // [k2][row] f16 pairs, [x|h]
  __shared__ __align__(16) u32   vcat2u[2 * 288];  // [x|h_lstm]
  __shared__ __align__(16) float zred[8 * 1024];   // [ks*2+row][1024 owned outputs]
  __shared__ __align__(16) float bbred[16 * 128];
  __shared__ __align__(16) float Ff[256];
  __shared__ __align__(16) u32   Fpk2u[2 * 64];
  __shared__ __align__(16) float zff[16 * 256];    // [kh*8+mat*2+row][256]

  const int j  = threadIdx.x;
  const int pb = blockIdx.x >> 1;
  const int g  = blockIdx.x & 1;
  const int bf16in = *flagp;

  // roles
  const int zs = j >> 8, zp = j & 255, zrun = zp >> 6, zq = zp & 63;
  const int zcol = zrun * 512 + g * 256 + zq * 4;     // owned Wz column base
  const int bs = j >> 7, bm = j & 127;                // backbone
  const int fmat = j >> 8, fkh = (j >> 7) & 1, fupl = j & 127;  // ff

  const int grow = j >> 7, glp = j & 127;             // gates/combine roles (j<256)
  float2 bgi, bgg, bgf, bgo, cb_f1, cb_f2, cb_ta, cb_tb;
  float c0 = 0.f, c1 = 0.f, bbbr = 0.f, hbr = 0.f;
  u32 hwreg[4];
  if (j < 256) {
    const int ub = g * 256 + 2 * glp;
    bgi = *(const float2*)(bif + 0 * DH + ub);
    bgg = *(const float2*)(bif + 1 * DH + ub);
    bgf = *(const float2*)(bif + 2 * DH + ub);
    bgo = *(const float2*)(bif + 3 * DH + ub);
    cb_f1 = *(const float2*)(ffbv + 0 * DH + ub);
    cb_f2 = *(const float2*)(ffbv + 1 * DH + ub);
    cb_ta = *(const float2*)(ffbv + 2 * DH + ub);
    cb_tb = *(const float2*)(ffbv + 3 * DH + ub);
    bbbr = bbbf[glp];
    const int w_ = (j >> 6) & 1, hl = j & 63;
#pragma unroll
    for (int i = 0; i < 4; ++i) hwreg[i] = hwp[w_ * 256 + hl + 64 * i];
    hbr = hbf[w_];
  }
  if (j < 512) zin2u[64 + j] = 0u;  // h0 = 0 (both rows)
  __syncthreads();

  for (int t = 0; t < TT; ++t) {
    const u32 tag = 0x51000000u + (u32)t;
    const int par = t & 1;

    // ---- stage x_t (2 rows) ----
    if (j < 64) {
      const int xr = j >> 5, xk = j & 31;
      const size_t xi = ((size_t)(pb * 2 + xr) * TT + t) * 32 + xk;
      u32 pk;
      if (bf16in) {
        const u32 w = ((const u32*)xraw)[xi];
        pk = packf16(bf2f((u16)(w & 0xffffu)), bf2f((u16)(w >> 16)));
      } else {
        const float2 v = ((const float2*)xraw)[xi];
        pk = packf16(v.x, v.y);
      }
      zin2u[2 * xk + xr] = pk;
      vcat2u[2 * xk + xr] = pk;
    }
    __syncthreads();

    // ---- Z: owned 1024 outputs x 2 rows; weight uint4 reused for both rows ----
    {
      float r0a = 0, r0b = 0, r0c = 0, r0d = 0, r1a = 0, r1b = 0, r1c = 0, r1d = 0;
      const u32* wp = wzp + (size_t)(zs * 72) * GZ + zcol;
      const uint2* ap = (const uint2*)zin2u + zs * 72;
#pragma unroll 4
      for (int k2 = 0; k2 < 72; ++k2) {
        const uint4 w = *(const uint4*)wp; wp += GZ;
        const uint2 a = ap[k2];
        r0a = dot2p(w.x, a.x, r0a); r0b = dot2p(w.y, a.x, r0b);
        r0c = dot2p(w.z, a.x, r0c); r0d = dot2p(w.w, a.x, r0d);
        r1a = dot2p(w.x, a.y, r1a); r1b = dot2p(w.y, a.y, r1b);
        r1c = dot2p(w.z, a.y, r1c); r1d = dot2p(w.w, a.y, r1d);
      }
      const int lo = zrun * 256 + zq * 4;
      *(float4*)(zred + (zs * 2 + 0) * 1024 + lo) = make_float4(r0a, r0b, r0c, r0d);
      *(float4*)(zred + (zs * 2 + 1) * 1024 + lo) = make_float4(r1a, r1b, r1c, r1d);
    }
    __syncthreads();

    // ---- LSTM gates + h_lstm exchange write ----
    if (j < 256) {
      float2 zi = bgi, zg = bgg, zf = bgf, zo = bgo;
#pragma unroll
      for (int sl = 0; sl < 4; ++sl) {
        const float* zr = zred + (sl * 2 + grow) * 1024 + 2 * glp;
        { const float2 v = *(const float2*)(zr + 0);   zi.x += v.x; zi.y += v.y; }
        { const float2 v = *(const float2*)(zr + 256); zg.x += v.x; zg.y += v.y; }
        { const float2 v = *(const float2*)(zr + 512); zf.x += v.x; zf.y += v.y; }
        { const float2 v = *(const float2*)(zr + 768); zo.x += v.x; zo.y += v.y; }
      }
      c0 = fmaf(c0, fsig(zf.x + 1.f), ftanh(zi.x) * fsig(zg.x));
      c1 = fmaf(c1, fsig(zf.y + 1.f), ftanh(zi.y) * fsig(zg.y));
      const u32 pk = packf16(ftanh(c0) * fsig(zo.x), ftanh(c1) * fsig(zo.y));
      vcat2u[2 * (32 + g * 128 + glp) + grow] = pk;
      __hip_atomic_store(&HL[((pb * 2 + par) * 2 + g) * 256 + j], pk,
                         __ATOMIC_RELAXED, __HIP_MEMORY_SCOPE_AGENT);
      __threadfence();
    }
    __syncthreads();
    if (j == 0)
      __hip_atomic_store(&FLG[((pb * 2 + 0) * 2 + par) * 2 + g], tag,
                         __ATOMIC_RELEASE, __HIP_MEMORY_SCOPE_AGENT);
    if (j < 256) {
      const u32* pf = &FLG[((pb * 2 + 0) * 2 + par) * 2 + (1 - g)];
      while (__hip_atomic_load(pf, __ATOMIC_ACQUIRE, __HIP_MEMORY_SCOPE_AGENT) != tag)
        __builtin_amdgcn_s_sleep(2);
      const u32 pk = __hip_atomic_load(&HL[((pb * 2 + par) * 2 + (1 - g)) * 256 + j],
                                       __ATOMIC_RELAXED, __HIP_MEMORY_SCOPE_AGENT);
      vcat2u[2 * (32 + (1 - g) * 128 + glp) + grow] = pk;
    }
    __syncthreads();

    // ---- backbone partials (full F, both rows) ----
    {
      float a0 = 0.f, a1 = 0.f;
      const u32* bp = bbp + (size_t)(bs * 36) * DB + bm;
      const uint2* vp = (const uint2*)vcat2u + bs * 36;
#pragma unroll 4
      for (int k2 = 0; k2 < 36; ++k2) {
        const u32 w = bp[(size_t)k2 * DB];
        const uint2 a = vp[k2];
        a0 = dot2p(w, a.x, a0);
        a1 = dot2p(w, a.y, a1);
      }
      bbred[(bs * 2 + 0) * DB + bm] = a0;
      bbred[(bs * 2 + 1) * DB + bm] = a1;
    }
    __syncthreads();
    if (j < 256) {
      float s = bbbr;
#pragma unroll
      for (int sl = 0; sl < 8; ++sl) s += bbred[(sl * 2 + grow) * DB + glp];
      Ff[grow * DB + glp] = 1.7159f * ftanh(0.666f * s);
    }
    __syncthreads();
    if (j < 64) {
      Fpk2u[2 * j + 0] = packf16(Ff[2 * j], Ff[2 * j + 1]);
      Fpk2u[2 * j + 1] = packf16(Ff[DB + 2 * j], Ff[DB + 2 * j + 1]);
    }
    __syncthreads();

    // ---- ff1/ff2/ta/tb on owned units (k split in halves) ----
    {
      float a00 = 0, a01 = 0, a10 = 0, a11 = 0;
      const u32* fp = ffp + (size_t)(fmat * 64 + fkh * 32) * DH + 2 * (g * 128 + fupl);
      const uint2* Fp = (const uint2*)Fpk2u + fkh * 32;
#pragma unroll 8
      for (int k2 = 0; k2 < 32; ++k2) {
        const uint2 w = *(const uint2*)fp; fp += DH;
        const uint2 a = Fp[k2];
        a00 = dot2p(w.x, a.x, a00); a01 = dot2p(w.x, a.y, a01);
        a10 = dot2p(w.y, a.x, a10); a11 = dot2p(w.y, a.y, a11);
      }
      *(float2*)(zff + (fkh * 8 + fmat * 2 + 0) * 256 + 2 * fupl) = make_float2(a00, a10);
      *(float2*)(zff + (fkh * 8 + fmat * 2 + 1) * 256 + 2 * fupl) = make_float2(a01, a11);
    }
    __syncthreads();

    // ---- combine -> h_new + exchange write (+ last_h) ----
    if (j < 256) {
      const int base = grow * 256 + 2 * glp;
      const float2 m0a = *(const float2*)(zff + base + 0 * 256);
      const float2 m0b = *(const float2*)(zff + base + 8 * 256);
      const float2 m1a = *(const float2*)(zff + base + 2 * 256);
      const float2 m1b = *(const float2*)(zff + base + 10 * 256);
      const float2 m2a = *(const float2*)(zff + base + 4 * 256);
      const float2 m2b = *(const float2*)(zff + base + 12 * 256);
      const float2 m3a = *(const float2*)(zff + base + 6 * 256);
      const float2 m3b = *(const float2*)(zff + base + 14 * 256);
      const float z1x = m0a.x + m0b.x + cb_f1.x, z1y = m0a.y + m0b.y + cb_f1.y;
      const float z2x = m1a.x + m1b.x + cb_f2.x, z2y = m1a.y + m1b.y + cb_f2.y;
      const float zax = m2a.x + m2b.x + cb_ta.x, zay = m2a.y + m2b.y + cb_ta.y;
      const float zbx = m3a.x + m3b.x + cb_tb.x, zby = m3a.y + m3b.y + cb_tb.y;
      const float ti0 = fsig(zax + zbx), ti1 = fsig(zay + zby);
      const float hn0 = fmaf(ftanh(z1x), 1.f - ti0, ti0 * ftanh(z2x));
      const float hn1 = fmaf(ftanh(z1y), 1.f - ti1, ti1 * ftanh(z2y));
      const u32 pk = packf16(hn0, hn1);
      zin2u[2 * (32 + g * 128 + glp) + grow] = pk;
      __hip_atomic_store(&HN[((pb * 2 + par) * 2 + g) * 256 + j], pk,
                         __ATOMIC_RELAXED, __HIP_MEMORY_SCOPE_AGENT);
      __threadfence();
      if (t == TT - 1) {
        float* lp = out + (size_t)NB * TT * 2 + (size_t)(pb * 2 + grow) * DH
                    + (g * 256 + 2 * glp);
        lp[0] = hn0; lp[1] = hn1;
      }
    }
    __syncthreads();
    if (j == 0)
      __hip_atomic_store(&FLG[((pb * 2 + 1) * 2 + par) * 2 + g], tag,
                         __ATOMIC_RELEASE, __HIP_MEMORY_SCOPE_AGENT);
    if (j < 256) {
      const u32* pf = &FLG[((pb * 2 + 1) * 2 + par) * 2 + (1 - g)];
      while (__hip_atomic_load(pf, __ATOMIC_ACQUIRE, __HIP_MEMORY_SCOPE_AGENT) != tag)
        __builtin_amdgcn_s_sleep(2);
      const u32 pk = __hip_atomic_load(&HN[((pb * 2 + par) * 2 + (1 - g)) * 256 + j],
                                       __ATOMIC_RELAXED, __HIP_MEMORY_SCOPE_AGENT);
      zin2u[2 * (32 + (1 - g) * 128 + glp) + grow] = pk;
    }
    __syncthreads();

    // ---- head (half 0 only; one wave per (row, output)) ----
    if (g == 0 && j < 256) {
      const int w_ = (j >> 6) & 1, hl = j & 63;
      float acc = 0.f;
#pragma unroll
      for (int i = 0; i < 4; ++i) {
        const uint2 hp = *(const uint2*)(zin2u + 2 * (32 + hl + 64 * i));
        acc = dot2p(hwreg[i], grow ? hp.y : hp.x, acc);
      }
#pragma unroll
      for (int off = 32; off > 0; off >>= 1) acc += __shfl_down(acc, off, 64);
      if (hl == 0) out[((size_t)(pb * 2 + grow) * TT + t) * 2 + w_] = acc + hbr;
    }
  }
}

// ---------------- fallback (round-3 verified, bf16 d_in, small ws) ----------------
__device__ __forceinline__ void fma8(float& acc, const uint4 u, const float* v) {
  union { u32 i; float f; } tt;
  tt.i = u.x << 16;          acc = fmaf(tt.f, v[0], acc);
  tt.i = u.x & 0xffff0000u;  acc = fmaf(tt.f, v[1], acc);
  tt.i = u.y << 16;          acc = fmaf(tt.f, v[2], acc);
  tt.i = u.y & 0xffff0000u;  acc = fmaf(tt.f, v[3], acc);
  tt.i = u.z << 16;          acc = fmaf(tt.f, v[4], acc);
  tt.i = u.z & 0xffff0000u;  acc = fmaf(tt.f, v[5], acc);
  tt.i = u.w << 16;          acc = fmaf(tt.f, v[6], acc);
  tt.i = u.w & 0xffff0000u;  acc = fmaf(tt.f, v[7], acc);
}
__global__ __launch_bounds__(256, 1)
void fb_scan(const u16* __restrict__ x,   const u16* __restrict__ Wi,
             const u16* __restrict__ bi,  const u16* __restrict__ Wh,
             const u16* __restrict__ bbW, const u16* __restrict__ bbb,
             const u16* __restrict__ f1W, const u16* __restrict__ f1b,
             const u16* __restrict__ f2W, const u16* __restrict__ f2b,
             const u16* __restrict__ taW, const u16* __restrict__ tab,
             const u16* __restrict__ tbW, const u16* __restrict__ tbb,
             const u16* __restrict__ hW,  const u16* __restrict__ hb,
             float* __restrict__ out)
{
  __shared__ __align__(16) float vcat[DI + DH];
  __shared__ __align__(16) float Fb2[DB];
  __shared__ __align__(16) float fpart[256];
  __shared__ __align__(16) float hprev[DH];
  const int j = threadIdx.x, b = blockIdx.x;
  const int u0 = j, u1 = j + 256;
  float bi_r[8];
#pragma unroll
  for (int k = 0; k < 8; ++k) bi_r[k] = bf2f(bi[j + 256 * k]);
  const float b_f1_0 = bf2f(f1b[u0]), b_f1_1 = bf2f(f1b[u1]);
  const float b_f2_0 = bf2f(f2b[u0]), b_f2_1 = bf2f(f2b[u1]);
  const float b_ta_0 = bf2f(tab[u0]), b_ta_1 = bf2f(tab[u1]);
  const float b_tb_0 = bf2f(tbb[u0]), b_tb_1 = bf2f(tbb[u1]);
  const float b_bb = (j < DB) ? bf2f(bbb[j]) : 0.f;
  float hwr[8]; float hbr = 0.f;
  if (j < 128) {
    const int w = j >> 6, l = j & 63;
#pragma unroll
    for (int q = 0; q < 8; ++q) hwr[q] = bf2f(hW[w * DH + q * 64 + l]);
    hbr = bf2f(hb[w]);
  }
  float c0 = 0.f, c1 = 0.f;
  hprev[u0] = 0.f; hprev[u1] = 0.f;
  const u16* xp = x + (size_t)b * TT * DI;
  __syncthreads();
  for (int t = 0; t < TT; ++t) {
    if (j < DI) vcat[j] = bf2f(xp[t * DI + j]);
    __syncthreads();
    float a[8];
#pragma unroll
    for (int k = 0; k < 8; ++k) a[k] = bi_r[k];
#pragma unroll
    for (int r = 0; r < 8; ++r) {
      const u16* wr = Wi + ((size_t)(j + 256 * r)) * DI;
      float acc = a[r];
#pragma unroll
      for (int kk = 0; kk < DI; kk += 8) fma8(acc, *(const uint4*)(wr + kk), vcat + kk);
      a[r] = acc;
    }
#pragma unroll 1
    for (int kb = 0; kb < DH; kb += 64) {
      float hreg[64];
#pragma unroll
      for (int q = 0; q < 16; ++q)
        *(float4*)(hreg + 4 * q) = *(const float4*)(hprev + kb + 4 * q);
#pragma unroll
      for (int r = 0; r < 8; ++r) {
        const u16* wr = Wh + ((size_t)(j + 256 * r)) * DH + kb;
        float acc = a[r];
#pragma unroll
        for (int cc = 0; cc < 8; ++cc) fma8(acc, *(const uint4*)(wr + 8 * cc), hreg + 8 * cc);
        a[r] = acc;
      }
    }
    {
      const float cn0 = fmaf(c0, fsig(a[4] + 1.f), ftanh(a[0]) * fsig(a[2]));
      const float cn1 = fmaf(c1, fsig(a[5] + 1.f), ftanh(a[1]) * fsig(a[3]));
      c0 = cn0; c1 = cn1;
      vcat[DI + u0] = ftanh(cn0) * fsig(a[6]);
      vcat[DI + u1] = ftanh(cn1) * fsig(a[7]);
    }
    __syncthreads();
    {
      const int mm = j & (DB - 1), pp = j >> 7;
      const u16* br = bbW + (size_t)mm * KZ + pp * 288;
      const float* vs = vcat + pp * 288;
      float s0 = 0.f, s1 = 0.f, s2v = 0.f, s3 = 0.f;
#pragma unroll
      for (int kk = 0; kk < 288; kk += 32) {
        fma8(s0, *(const uint4*)(br + kk), vs + kk);
        fma8(s1, *(const uint4*)(br + kk + 8), vs + kk + 8);
        fma8(s2v, *(const uint4*)(br + kk + 16), vs + kk + 16);
        fma8(s3, *(const uint4*)(br + kk + 24), vs + kk + 24);
      }
      fpart[j] = (s0 + s1) + (s2v + s3);
    }
    __syncthreads();
    if (j < DB) Fb2[j] = 1.7159f * ftanh(0.666f * (b_bb + fpart[j] + fpart[j + DB]));
    __syncthreads();
    {
      float Fr[DB];
#pragma unroll
      for (int q = 0; q < 32; ++q) *(float4*)(Fr + 4 * q) = *(const float4*)(Fb2 + 4 * q);
      const u16* rp[8] = {
        f1W + (size_t)u0 * DB, f1W + (size_t)u1 * DB,
        f2W + (size_t)u0 * DB, f2W + (size_t)u1 * DB,
        taW + (size_t)u0 * DB, taW + (size_t)u1 * DB,
        tbW + (size_t)u0 * DB, tbW + (size_t)u1 * DB };
      float sacc[8] = { b_f1_0, b_f1_1, b_f2_0, b_f2_1, b_ta_0, b_ta_1, b_tb_0, b_tb_1 };
#pragma unroll
      for (int rr = 0; rr < 8; ++rr) {
        float acc = sacc[rr];
        const u16* r = rp[rr];
#pragma unroll
        for (int kk = 0; kk < DB; kk += 8) fma8(acc, *(const uint4*)(r + kk), Fr + kk);
        sacc[rr] = acc;
      }
      const float ti0 = fsig(sacc[4] + sacc[6]);
      const float ti1 = fsig(sacc[5] + sacc[7]);
      hprev[u0] = fmaf(ftanh(sacc[0]), 1.f - ti0, ti0 * ftanh(sacc[2]));
      hprev[u1] = fmaf(ftanh(sacc[1]), 1.f - ti1, ti1 * ftanh(sacc[3]));
    }
    __syncthreads();
    if (j < 128) {
      const int l = j & 63;
      float acc = 0.f;
#pragma unroll
      for (int q = 0; q < 8; ++q) acc = fmaf(hprev[q * 64 + l], hwr[q], acc);
#pragma unroll
      for (int off = 32; off > 0; off >>= 1) acc += __shfl_down(acc, off, 64);
      if (l == 0) out[((size_t)b * TT + t) * 2 + (j >> 6)] = acc + hbr;
    }
  }
  out[(size_t)NB * TT * 2 + (size_t)b * DH + u0] = hprev[u0];
  out[(size_t)NB * TT * 2 + (size_t)b * DH + u1] = hprev[u1];
}

extern "C" void kernel_launch(void* const* d_in, const int* in_sizes, int n_in,
                              void* d_out, int out_size, void* d_ws, size_t ws_size,
                              hipStream_t stream) {
  (void)in_sizes; (void)n_in; (void)out_size;

  if (ws_size >= WS_NEED) {
    char* ws = (char*)d_ws;
    int* flag = (int*)ws;
    detect_kernel<<<dim3(1), dim3(64), 0, stream>>>(
        (const u16*)d_in[0], (const u16*)d_in[1], (const u16*)d_in[3], flag);
    pwz_kernel<<<dim3(8, 288), dim3(256), 0, stream>>>(d_in[1], d_in[3], flag,
                                                       (u32*)(ws + O_WZP));
    pbb_kernel<<<dim3(288), dim3(128), 0, stream>>>(d_in[4], flag, (u32*)(ws + O_BBP));
    pff_kernel<<<dim3(2, 64, 4), dim3(256), 0, stream>>>(d_in[6], d_in[8], d_in[10],
                                                         d_in[12], flag, (u32*)(ws + O_FFP));
    psmall_kernel<<<dim3(1), dim3(1024), 0, stream>>>(
        d_in[2], d_in[7], d_in[9], d_in[11], d_in[13], d_in[5], d_in[14], d_in[15],
        flag, (float*)(ws + O_BIF), (float*)(ws + O_FFB), (float*)(ws + O_BBBF),
        (u32*)(ws + O_HWP), (float*)(ws + O_HBF));

    scan_pair<<<dim3(NB), dim3(NT), 0, stream>>>(
        d_in[0], flag,
        (const u32*)(ws + O_WZP), (const u32*)(ws + O_BBP), (const u32*)(ws + O_FFP),
        (const float*)(ws + O_BIF), (const float*)(ws + O_FFB),
        (const float*)(ws + O_BBBF), (const u32*)(ws + O_HWP),
        (const float*)(ws + O_HBF),
        (u32*)(ws + O_HL), (u32*)(ws + O_HN), (u32*)(ws + O_FLG),
        (float*)d_out);
  } else {
    fb_scan<<<dim3(NB), dim3(256), 0, stream>>>(
        (const u16*)d_in[0],  (const u16*)d_in[1],  (const u16*)d_in[2],
        (const u16*)d_in[3],  (const u16*)d_in[4],  (const u16*)d_in[5],
        (const u16*)d_in[6],  (const u16*)d_in[7],  (const u16*)d_in[8],
        (const u16*)d_in[9],  (const u16*)d_in[10], (const u16*)d_in[11],
        (const u16*)d_in[12], (const u16*)d_in[13], (const u16*)d_in[14],
        (const u16*)d_in[15], (float*)d_out);
  }
}

// Round 7
// 26335.449 us; speedup vs baseline: 1.5586x; 1.5586x over previous
//
#include <hip/hip_runtime.h>

#define NB 128
#define TT 1024
#define DI 64
#define DH 512
#define DB 128
#define GZ 2048
#define KZ 576

typedef unsigned short u16;
typedef unsigned int u32;
typedef unsigned long long u64;

#if defined(__has_builtin)
#if __has_builtin(__builtin_amdgcn_fdot2)
#define HAS_FDOT2 1
#endif
#endif

typedef _Float16 half2v __attribute__((ext_vector_type(2)));

__device__ __forceinline__ float bf2f(u16 u) {
  union { u32 i; float f; } v; v.i = ((u32)u) << 16; return v.f;
}
__device__ __forceinline__ float fsig(float x) {
  return __builtin_amdgcn_rcpf(1.f + __expf(-x));
}
__device__ __forceinline__ float ftanh(float x) {
  return 1.f - 2.f * __builtin_amdgcn_rcpf(__expf(2.f * x) + 1.f);
}
__device__ __forceinline__ float dot2p(u32 w, u32 a, float acc) {
#ifdef HAS_FDOT2
  return __builtin_amdgcn_fdot2(__builtin_bit_cast(half2v, w),
                                __builtin_bit_cast(half2v, a), acc, false);
#else
  half2v hw = __builtin_bit_cast(half2v, w), ha = __builtin_bit_cast(half2v, a);
  acc = fmaf((float)hw.x, (float)ha.x, acc);
  return fmaf((float)hw.y, (float)ha.y, acc);
#endif
}
__device__ __forceinline__ u32 packf16(float x, float y) {
  half2v h; h.x = (_Float16)x; h.y = (_Float16)y;
  return __builtin_bit_cast(u32, h);
}

// ---- ws layout (bytes, 256-aligned) — identical to round 5 (validated) ----
#define O_WZP  256
#define O_BBP  (O_WZP + 2359296)
#define O_FFP  (O_BBP + 147456)
#define O_BIF  (O_FFP + 524288)
#define O_FFB  (O_BIF + 8192)
#define O_BBBF (O_FFB + 8192)
#define O_HWP  (O_BBBF + 512)
#define O_HBF  (O_HWP + 2048)
#define WS_NEED ((u64)(O_HBF + 256))   // ~3.05 MB

// ---------------- dtype detection (validated rounds 3-6) ----------------
__global__ void detect_kernel(const u16* x, const u16* wi, const u16* wh, int* flag) {
  const int l = threadIdx.x;
  int cnt = (((x[2 * l] >> 7) & 0xFF) < 134)
          + (((wi[2 * l] >> 7) & 0xFF) < 134)
          + (((wh[2 * l] >> 7) & 0xFF) < 134);
#pragma unroll
  for (int off = 32; off > 0; off >>= 1) cnt += __shfl_down(cnt, off, 64);
  if (l == 0) *flag = (cnt >= 180) ? 1 : 0;
}

__device__ __forceinline__ float ldf(int f, const void* s, u32 i) {
  return f ? bf2f(((const u16*)s)[i]) : ((const float*)s)[i];
}

// ---- prep kernels (validated in rounds 5/6) ----
__global__ void pwz_kernel(const void* Wi, const void* Wh,
                           const int* __restrict__ flag, u32* __restrict__ wzp) {
  const int o = blockIdx.x * 256 + threadIdx.x;
  const int k2 = blockIdx.y;
  const int f = *flag;
  float a, b;
  if (k2 < 32) {
    const u32 i = (u32)o * DI + 2 * k2;
    a = ldf(f, Wi, i); b = ldf(f, Wi, i + 1);
  } else {
    const u32 i = (u32)o * DH + 2 * (k2 - 32);
    a = ldf(f, Wh, i); b = ldf(f, Wh, i + 1);
  }
  wzp[(u32)k2 * GZ + o] = packf16(a, b);
}
__global__ void pbb_kernel(const void* bb, const int* __restrict__ flag,
                           u32* __restrict__ bbp) {
  const int m = threadIdx.x;
  const int k2 = blockIdx.x;
  const int f = *flag;
  const u32 i = (u32)m * KZ + 2 * k2;
  bbp[(u32)k2 * DB + m] = packf16(ldf(f, bb, i), ldf(f, bb, i + 1));
}
__global__ void pff_kernel(const void* f1, const void* f2, const void* ta,
                           const void* tb, const int* __restrict__ flag,
                           u32* __restrict__ ffp) {
  const int o = blockIdx.x * 256 + threadIdx.x;
  const int k2 = blockIdx.y;
  const int mat = blockIdx.z;
  const void* s = (mat == 0) ? f1 : (mat == 1) ? f2 : (mat == 2) ? ta : tb;
  const int f = *flag;
  const u32 i = (u32)o * DB + 2 * k2;
  ffp[((u32)mat * 64 + k2) * DH + o] = packf16(ldf(f, s, i), ldf(f, s, i + 1));
}
__global__ void psmall_kernel(const void* bi_s, const void* f1b_s, const void* f2b_s,
                              const void* tab_s, const void* tbb_s, const void* bbb_s,
                              const void* hw_s, const void* hb_s,
                              const int* __restrict__ flag,
                              float* __restrict__ bif, float* __restrict__ ffb,
                              float* __restrict__ bbbf, u32* __restrict__ hwp,
                              float* __restrict__ hbf) {
  const int f = *flag;
  for (int i = threadIdx.x; i < 2048; i += 1024) {
    bif[i] = ldf(f, bi_s, i);
    if (i < 512) {
      ffb[i]        = ldf(f, f1b_s, i);
      ffb[512 + i]  = ldf(f, f2b_s, i);
      ffb[1024 + i] = ldf(f, tab_s, i);
      ffb[1536 + i] = ldf(f, tbb_s, i);
      const int w = i >> 8, pr = i & 255;
      hwp[i] = packf16(ldf(f, hw_s, w * DH + 2 * pr), ldf(f, hw_s, w * DH + 2 * pr + 1));
    }
    if (i < 128) bbbf[i] = ldf(f, bbb_s, i);
    if (i < 2)   hbf[i] = ldf(f, hb_s, i);
  }
}

// ---------------- main scan: 64 blocks x 2 rows, weights reused in-register ----------------
__global__ __launch_bounds__(1024, 1)
void scan2(const void* __restrict__ xraw, const int* __restrict__ flagp,
           const u32* __restrict__ wzp, const u32* __restrict__ bbp,
           const u32* __restrict__ ffp,
           const float* __restrict__ bif, const float* __restrict__ ffbv,
           const float* __restrict__ bbbf, const u32* __restrict__ hwp,
           const float* __restrict__ hbf, float* __restrict__ out)
{
  __shared__ __align__(16) u32   zin2u[288 * 2];     // [k2][row] pairs, [x|h]
  __shared__ __align__(16) u32   vcat2u[288 * 2];    // [x|h_lstm]
  __shared__ __align__(16) float zred[2 * 2 * GZ];   // [(slice*2+row)][2048] 32 KB
  __shared__ __align__(16) float bbred[8 * 2 * DB];  // 8 KB
  __shared__ __align__(16) u32   Fpk2u[64 * 2];      // [k2][row]
  __shared__ __align__(16) float zff[4 * 2 * DH];    // 16 KB

  const int j = threadIdx.x;
  const int b = blockIdx.x;          // 0..63; rows 2b, 2b+1
  const int bf16in = *flagp;

  const int zs = j >> 9, zp = j & 511;          // Z: 2 slices x 512 output-quads
  const int bs = j >> 7, bm = j & 127;          // bb: 8 slices x 128 outputs
  const int fmat = j >> 8, fp = j & 255;        // ff: 4 mats x 256 out-pairs
  const int grow = j >> 8, gup = j & 255;       // gates/combine (j<512)
  const int frow = j >> 6, fk2 = j & 63;        // Fpk (j<128)
  const int hrow = j >> 7, hw_ = (j >> 6) & 1, hl = j & 63;  // head (j<256)

  float2 bgi, bgg, bgf, bgo, cbf1, cbf2, cbta, cbtb;
  float c0 = 0.f, c1 = 0.f;
  if (j < 512) {
    bgi  = *(const float2*)(bif  + 0 * DH + 2 * gup);
    bgg  = *(const float2*)(bif  + 1 * DH + 2 * gup);
    bgf  = *(const float2*)(bif  + 2 * DH + 2 * gup);
    bgo  = *(const float2*)(bif  + 3 * DH + 2 * gup);
    cbf1 = *(const float2*)(ffbv + 0 * DH + 2 * gup);
    cbf2 = *(const float2*)(ffbv + 1 * DH + 2 * gup);
    cbta = *(const float2*)(ffbv + 2 * DH + 2 * gup);
    cbtb = *(const float2*)(ffbv + 3 * DH + 2 * gup);
  }
  float bbr0 = 0.f, bbr1 = 0.f;
  if (j < 128) { bbr0 = bbbf[2 * fk2]; bbr1 = bbbf[2 * fk2 + 1]; }
  u32 hwreg[4]; float hbr = 0.f;
  if (j < 256) {
#pragma unroll
    for (int i = 0; i < 4; ++i) hwreg[i] = hwp[hw_ * 256 + hl + 64 * i];
    hbr = hbf[hw_];
  }

  // h0 = 0 (both rows) + stage x(t=0)
  if (j < 512) zin2u[(32 + (j & 255)) * 2 + (j >> 8)] = 0u;
  if (j < 64) {
    const int xr = j >> 5, xk = j & 31;
    const size_t xi = ((size_t)(2 * b + xr) * TT + 0) * 32 + xk;
    u32 pk;
    if (bf16in) {
      const u32 w = ((const u32*)xraw)[xi];
      pk = packf16(bf2f((u16)(w & 0xffffu)), bf2f((u16)(w >> 16)));
    } else {
      const float2 v = ((const float2*)xraw)[xi];
      pk = packf16(v.x, v.y);
    }
    zin2u[xk * 2 + xr] = pk;
  }
  __syncthreads();

  for (int t = 0; t < TT; ++t) {
    // x slots of vcat (backbone input) — copy from zin (cheap, avoids extra barrier)
    if (j < 32) vcat2u[j * 2 + 0] = zin2u[j * 2 + 0];
    else if (j < 64) vcat2u[(j - 32) * 2 + 1] = zin2u[(j - 32) * 2 + 1];

    // ---- Z: [x|h] @ Wz; thread owns cols 4zp..4zp+3, k-rows zs*144..+143; 2 rows ----
    {
      float a0 = 0, a1 = 0, a2 = 0, a3 = 0, a4 = 0, a5 = 0, a6 = 0, a7 = 0;
      const u32* wp = wzp + (size_t)(zs * 144) * GZ + 4 * zp;
      const uint2* ap = (const uint2*)zin2u + zs * 144;
#pragma unroll 8
      for (int k2 = 0; k2 < 144; ++k2) {
        const uint4 w = *(const uint4*)wp; wp += GZ;
        const uint2 a = ap[k2];
        a0 = dot2p(w.x, a.x, a0); a1 = dot2p(w.y, a.x, a1);
        a2 = dot2p(w.z, a.x, a2); a3 = dot2p(w.w, a.x, a3);
        a4 = dot2p(w.x, a.y, a4); a5 = dot2p(w.y, a.y, a5);
        a6 = dot2p(w.z, a.y, a6); a7 = dot2p(w.w, a.y, a7);
      }
      *(float4*)(zred + (zs * 2 + 0) * GZ + 4 * zp) = make_float4(a0, a1, a2, a3);
      *(float4*)(zred + (zs * 2 + 1) * GZ + 4 * zp) = make_float4(a4, a5, a6, a7);
    }
    __syncthreads();                                   // (1) zred ready

    // ---- LSTM gates: thread (grow,gup) owns unit pair (2gup,2gup+1) of its row ----
    if (j < 512) {
      float2 zi = bgi, zg = bgg, zf = bgf, zo = bgo;
#pragma unroll
      for (int sl = 0; sl < 2; ++sl) {
        const float* zr = zred + (sl * 2 + grow) * GZ + 2 * gup;
        { const float2 v = *(const float2*)(zr);        zi.x += v.x; zi.y += v.y; }
        { const float2 v = *(const float2*)(zr + 512);  zg.x += v.x; zg.y += v.y; }
        { const float2 v = *(const float2*)(zr + 1024); zf.x += v.x; zf.y += v.y; }
        { const float2 v = *(const float2*)(zr + 1536); zo.x += v.x; zo.y += v.y; }
      }
      c0 = fmaf(c0, fsig(zf.x + 1.f), ftanh(zi.x) * fsig(zg.x));
      c1 = fmaf(c1, fsig(zf.y + 1.f), ftanh(zi.y) * fsig(zg.y));
      vcat2u[(32 + gup) * 2 + grow] = packf16(ftanh(c0) * fsig(zo.x),
                                              ftanh(c1) * fsig(zo.y));
    }
    __syncthreads();                                   // (2) h_lstm ready

    // ---- backbone partials: weight reused for both rows ----
    {
      float a0 = 0.f, a1 = 0.f;
      const u32* bp = bbp + (size_t)(bs * 36) * DB + bm;
      const uint2* vp = (const uint2*)vcat2u + bs * 36;
#pragma unroll 6
      for (int q = 0; q < 36; ++q) {
        const u32 w = bp[(size_t)q * DB];
        const uint2 a = vp[q];
        a0 = dot2p(w, a.x, a0);
        a1 = dot2p(w, a.y, a1);
      }
      bbred[(bs * 2 + 0) * DB + bm] = a0;
      bbred[(bs * 2 + 1) * DB + bm] = a1;
    }
    __syncthreads();                                   // (3) bb partials

    // ---- F reduce + lecun_tanh + pack (both rows) ----
    if (j < 128) {
      float r0 = bbr0, r1 = bbr1;
#pragma unroll
      for (int sl = 0; sl < 8; ++sl) {
        const float2 v = *(const float2*)(bbred + (sl * 2 + frow) * DB + 2 * fk2);
        r0 += v.x; r1 += v.y;
      }
      Fpk2u[fk2 * 2 + frow] = packf16(1.7159f * ftanh(0.666f * r0),
                                      1.7159f * ftanh(0.666f * r1));
    }
    __syncthreads();                                   // (4) F ready

    // ---- ff1/ff2/ta/tb: weight uint2 reused for both rows ----
    {
      float z00 = 0, z01 = 0, z10 = 0, z11 = 0;
      const u32* fpw = ffp + (size_t)(fmat * 64) * DH + 2 * fp;
      const uint2* Fp = (const uint2*)Fpk2u;
#pragma unroll 8
      for (int k2 = 0; k2 < 64; ++k2) {
        const uint2 w = *(const uint2*)fpw; fpw += DH;
        const uint2 a = Fp[k2];
        z00 = dot2p(w.x, a.x, z00); z01 = dot2p(w.x, a.y, z01);
        z10 = dot2p(w.y, a.x, z10); z11 = dot2p(w.y, a.y, z11);
      }
      *(float2*)(zff + (fmat * 2 + 0) * DH + 2 * fp) = make_float2(z00, z10);
      *(float2*)(zff + (fmat * 2 + 1) * DH + 2 * fp) = make_float2(z01, z11);
    }
    __syncthreads();                                   // (5) zff ready

    // ---- combine -> h_new (j<512)  ||  stage x(t+1) (j in [512,576)) ----
    if (j < 512) {
      const float2 v1 = *(const float2*)(zff + (0 * 2 + grow) * DH + 2 * gup);
      const float2 v2 = *(const float2*)(zff + (1 * 2 + grow) * DH + 2 * gup);
      const float2 va = *(const float2*)(zff + (2 * 2 + grow) * DH + 2 * gup);
      const float2 vb = *(const float2*)(zff + (3 * 2 + grow) * DH + 2 * gup);
      const float z1x = v1.x + cbf1.x, z1y = v1.y + cbf1.y;
      const float z2x = v2.x + cbf2.x, z2y = v2.y + cbf2.y;
      const float zax = va.x + cbta.x, zay = va.y + cbta.y;
      const float zbx = vb.x + cbtb.x, zby = vb.y + cbtb.y;
      const float ti0 = fsig(zax + zbx), ti1 = fsig(zay + zby);
      const float hn0 = fmaf(ftanh(z1x), 1.f - ti0, ti0 * ftanh(z2x));
      const float hn1 = fmaf(ftanh(z1y), 1.f - ti1, ti1 * ftanh(z2y));
      zin2u[(32 + gup) * 2 + grow] = packf16(hn0, hn1);
      if (t == TT - 1) {
        float* lp = out + (size_t)NB * TT * 2 + (size_t)(2 * b + grow) * DH + 2 * gup;
        lp[0] = hn0; lp[1] = hn1;
      }
    } else if (j < 576 && t + 1 < TT) {
      const int xr = (j - 512) >> 5, xk = (j - 512) & 31;
      const size_t xi = ((size_t)(2 * b + xr) * TT + (t + 1)) * 32 + xk;
      u32 pk;
      if (bf16in) {
        const u32 w = ((const u32*)xraw)[xi];
        pk = packf16(bf2f((u16)(w & 0xffffu)), bf2f((u16)(w >> 16)));
      } else {
        const float2 v = ((const float2*)xraw)[xi];
        pk = packf16(v.x, v.y);
      }
      zin2u[xk * 2 + xr] = pk;
    }
    __syncthreads();                                   // (6) h_new + x(t+1) ready

    // ---- head: runs in the shadow of next Z (no extra barrier) ----
    if (j < 256) {
      float acc = 0.f;
#pragma unroll
      for (int i = 0; i < 4; ++i)
        acc = dot2p(hwreg[i], zin2u[(32 + hl + 64 * i) * 2 + hrow], acc);
#pragma unroll
      for (int off = 32; off > 0; off >>= 1) acc += __shfl_down(acc, off, 64);
      if (hl == 0) out[((size_t)(2 * b + hrow) * TT + t) * 2 + hw_] = acc + hbr;
    }
  }
}

// ---------------- fallback (round-3 verified, bf16 d_in, small ws) ----------------
__device__ __forceinline__ void fma8(float& acc, const uint4 u, const float* v) {
  union { u32 i; float f; } tt;
  tt.i = u.x << 16;          acc = fmaf(tt.f, v[0], acc);
  tt.i = u.x & 0xffff0000u;  acc = fmaf(tt.f, v[1], acc);
  tt.i = u.y << 16;          acc = fmaf(tt.f, v[2], acc);
  tt.i = u.y & 0xffff0000u;  acc = fmaf(tt.f, v[3], acc);
  tt.i = u.z << 16;          acc = fmaf(tt.f, v[4], acc);
  tt.i = u.z & 0xffff0000u;  acc = fmaf(tt.f, v[5], acc);
  tt.i = u.w << 16;          acc = fmaf(tt.f, v[6], acc);
  tt.i = u.w & 0xffff0000u;  acc = fmaf(tt.f, v[7], acc);
}
__global__ __launch_bounds__(256, 1)
void fb_scan(const u16* __restrict__ x,   const u16* __restrict__ Wi,
             const u16* __restrict__ bi,  const u16* __restrict__ Wh,
             const u16* __restrict__ bbW, const u16* __restrict__ bbb,
             const u16* __restrict__ f1W, const u16* __restrict__ f1b,
             const u16* __restrict__ f2W, const u16* __restrict__ f2b,
             const u16* __restrict__ taW, const u16* __restrict__ tab,
             const u16* __restrict__ tbW, const u16* __restrict__ tbb,
             const u16* __restrict__ hW,  const u16* __restrict__ hb,
             float* __restrict__ out)
{
  __shared__ __align__(16) float vcat[DI + DH];
  __shared__ __align__(16) float Fb2[DB];
  __shared__ __align__(16) float fpart[256];
  __shared__ __align__(16) float hprev[DH];
  const int j = threadIdx.x, b = blockIdx.x;
  const int u0 = j, u1 = j + 256;
  float bi_r[8];
#pragma unroll
  for (int k = 0; k < 8; ++k) bi_r[k] = bf2f(bi[j + 256 * k]);
  const float b_f1_0 = bf2f(f1b[u0]), b_f1_1 = bf2f(f1b[u1]);
  const float b_f2_0 = bf2f(f2b[u0]), b_f2_1 = bf2f(f2b[u1]);
  const float b_ta_0 = bf2f(tab[u0]), b_ta_1 = bf2f(tab[u1]);
  const float b_tb_0 = bf2f(tbb[u0]), b_tb_1 = bf2f(tbb[u1]);
  const float b_bb = (j < DB) ? bf2f(bbb[j]) : 0.f;
  float hwr[8]; float hbr = 0.f;
  if (j < 128) {
    const int w = j >> 6, l = j & 63;
#pragma unroll
    for (int q = 0; q < 8; ++q) hwr[q] = bf2f(hW[w * DH + q * 64 + l]);
    hbr = bf2f(hb[w]);
  }
  float c0 = 0.f, c1 = 0.f;
  hprev[u0] = 0.f; hprev[u1] = 0.f;
  const u16* xp = x + (size_t)b * TT * DI;
  __syncthreads();
  for (int t = 0; t < TT; ++t) {
    if (j < DI) vcat[j] = bf2f(xp[t * DI + j]);
    __syncthreads();
    float a[8];
#pragma unroll
    for (int k = 0; k < 8; ++k) a[k] = bi_r[k];
#pragma unroll
    for (int r = 0; r < 8; ++r) {
      const u16* wr = Wi + ((size_t)(j + 256 * r)) * DI;
      float acc = a[r];
#pragma unroll
      for (int kk = 0; kk < DI; kk += 8) fma8(acc, *(const uint4*)(wr + kk), vcat + kk);
      a[r] = acc;
    }
#pragma unroll 1
    for (int kb = 0; kb < DH; kb += 64) {
      float hreg[64];
#pragma unroll
      for (int q = 0; q < 16; ++q)
        *(float4*)(hreg + 4 * q) = *(const float4*)(hprev + kb + 4 * q);
#pragma unroll
      for (int r = 0; r < 8; ++r) {
        const u16* wr = Wh + ((size_t)(j + 256 * r)) * DH + kb;
        float acc = a[r];
#pragma unroll
        for (int cc = 0; cc < 8; ++cc) fma8(acc, *(const uint4*)(wr + 8 * cc), hreg + 8 * cc);
        a[r] = acc;
      }
    }
    {
      const float cn0 = fmaf(c0, fsig(a[4] + 1.f), ftanh(a[0]) * fsig(a[2]));
      const float cn1 = fmaf(c1, fsig(a[5] + 1.f), ftanh(a[1]) * fsig(a[3]));
      c0 = cn0; c1 = cn1;
      vcat[DI + u0] = ftanh(cn0) * fsig(a[6]);
      vcat[DI + u1] = ftanh(cn1) * fsig(a[7]);
    }
    __syncthreads();
    {
      const int mm = j & (DB - 1), pp = j >> 7;
      const u16* br = bbW + (size_t)mm * KZ + pp * 288;
      const float* vs = vcat + pp * 288;
      float s0 = 0.f, s1 = 0.f, s2v = 0.f, s3 = 0.f;
#pragma unroll
      for (int kk = 0; kk < 288; kk += 32) {
        fma8(s0, *(const uint4*)(br + kk), vs + kk);
        fma8(s1, *(const uint4*)(br + kk + 8), vs + kk + 8);
        fma8(s2v, *(const uint4*)(br + kk + 16), vs + kk + 16);
        fma8(s3, *(const uint4*)(br + kk + 24), vs + kk + 24);
      }
      fpart[j] = (s0 + s1) + (s2v + s3);
    }
    __syncthreads();
    if (j < DB) Fb2[j] = 1.7159f * ftanh(0.666f * (b_bb + fpart[j] + fpart[j + DB]));
    __syncthreads();
    {
      float Fr[DB];
#pragma unroll
      for (int q = 0; q < 32; ++q) *(float4*)(Fr + 4 * q) = *(const float4*)(Fb2 + 4 * q);
      const u16* rp[8] = {
        f1W + (size_t)u0 * DB, f1W + (size_t)u1 * DB,
        f2W + (size_t)u0 * DB, f2W + (size_t)u1 * DB,
        taW + (size_t)u0 * DB, taW + (size_t)u1 * DB,
        tbW + (size_t)u0 * DB, tbW + (size_t)u1 * DB };
      float sacc[8] = { b_f1_0, b_f1_1, b_f2_0, b_f2_1, b_ta_0, b_ta_1, b_tb_0, b_tb_1 };
#pragma unroll
      for (int rr = 0; rr < 8; ++rr) {
        float acc = sacc[rr];
        const u16* r = rp[rr];
#pragma unroll
        for (int kk = 0; kk < DB; kk += 8) fma8(acc, *(const uint4*)(r + kk), Fr + kk);
        sacc[rr] = acc;
      }
      const float ti0 = fsig(sacc[4] + sacc[6]);
      const float ti1 = fsig(sacc[5] + sacc[7]);
      hprev[u0] = fmaf(ftanh(sacc[0]), 1.f - ti0, ti0 * ftanh(sacc[2]));
      hprev[u1] = fmaf(ftanh(sacc[1]), 1.f - ti1, ti1 * ftanh(sacc[3]));
    }
    __syncthreads();
    if (j < 128) {
      const int l = j & 63;
      float acc = 0.f;
#pragma unroll
      for (int q = 0; q < 8; ++q) acc = fmaf(hprev[q * 64 + l], hwr[q], acc);
#pragma unroll
      for (int off = 32; off > 0; off >>= 1) acc += __shfl_down(acc, off, 64);
      if (l == 0) out[((size_t)b * TT + t) * 2 + (j >> 6)] = acc + hbr;
    }
  }
  out[(size_t)NB * TT * 2 + (size_t)b * DH + u0] = hprev[u0];
  out[(size_t)NB * TT * 2 + (size_t)b * DH + u1] = hprev[u1];
}

extern "C" void kernel_launch(void* const* d_in, const int* in_sizes, int n_in,
                              void* d_out, int out_size, void* d_ws, size_t ws_size,
                              hipStream_t stream) {
  (void)in_sizes; (void)n_in; (void)out_size;

  if (ws_size >= WS_NEED) {
    char* ws = (char*)d_ws;
    int* flag = (int*)ws;
    detect_kernel<<<dim3(1), dim3(64), 0, stream>>>(
        (const u16*)d_in[0], (const u16*)d_in[1], (const u16*)d_in[3], flag);
    pwz_kernel<<<dim3(8, 288), dim3(256), 0, stream>>>(d_in[1], d_in[3], flag,
                                                       (u32*)(ws + O_WZP));
    pbb_kernel<<<dim3(288), dim3(128), 0, stream>>>(d_in[4], flag, (u32*)(ws + O_BBP));
    pff_kernel<<<dim3(2, 64, 4), dim3(256), 0, stream>>>(d_in[6], d_in[8], d_in[10],
                                                         d_in[12], flag, (u32*)(ws + O_FFP));
    psmall_kernel<<<dim3(1), dim3(1024), 0, stream>>>(
        d_in[2], d_in[7], d_in[9], d_in[11], d_in[13], d_in[5], d_in[14], d_in[15],
        flag, (float*)(ws + O_BIF), (float*)(ws + O_FFB), (float*)(ws + O_BBBF),
        (u32*)(ws + O_HWP), (float*)(ws + O_HBF));

    scan2<<<dim3(64), dim3(1024), 0, stream>>>(
        d_in[0], flag,
        (const u32*)(ws + O_WZP), (const u32*)(ws + O_BBP), (const u32*)(ws + O_FFP),
        (const float*)(ws + O_BIF), (const float*)(ws + O_FFB),
        (const float*)(ws + O_BBBF), (const u32*)(ws + O_HWP),
        (const float*)(ws + O_HBF), (float*)d_out);
  } else {
    fb_scan<<<dim3(NB), dim3(256), 0, stream>>>(
        (const u16*)d_in[0],  (const u16*)d_in[1],  (const u16*)d_in[2],
        (const u16*)d_in[3],  (const u16*)d_in[4],  (const u16*)d_in[5],
        (const u16*)d_in[6],  (const u16*)d_in[7],  (const u16*)d_in[8],
        (const u16*)d_in[9],  (const u16*)d_in[10], (const u16*)d_in[11],
        (const u16*)d_in[12], (const u16*)d_in[13], (const u16*)d_in[14],
        (const u16*)d_in[15], (float*)d_out);
  }
}

// Round 8
// 23717.265 us; speedup vs baseline: 1.7307x; 1.1104x over previous
//
#include <hip/hip_runtime.h>

#define NB 128
#define TT 1024
#define DI 64
#define DH 512
#define DB 128
#define GZ 2048
#define KZ 576

typedef unsigned short u16;
typedef unsigned int u32;
typedef unsigned long long u64;

#if defined(__has_builtin)
#if __has_builtin(__builtin_amdgcn_fdot2)
#define HAS_FDOT2 1
#endif
#if __has_builtin(__builtin_amdgcn_sdot4)
#define HAS_SDOT4 1
#endif
#endif

typedef _Float16 half2v __attribute__((ext_vector_type(2)));

__device__ __forceinline__ float bf2f(u16 u) {
  union { u32 i; float f; } v; v.i = ((u32)u) << 16; return v.f;
}
__device__ __forceinline__ float fsig(float x) {
  return __builtin_amdgcn_rcpf(1.f + __expf(-x));
}
__device__ __forceinline__ float ftanh(float x) {
  return 1.f - 2.f * __builtin_amdgcn_rcpf(__expf(2.f * x) + 1.f);
}
__device__ __forceinline__ float dot2p(u32 w, u32 a, float acc) {
#ifdef HAS_FDOT2
  return __builtin_amdgcn_fdot2(__builtin_bit_cast(half2v, w),
                                __builtin_bit_cast(half2v, a), acc, false);
#else
  half2v hw = __builtin_bit_cast(half2v, w), ha = __builtin_bit_cast(half2v, a);
  acc = fmaf((float)hw.x, (float)ha.x, acc);
  return fmaf((float)hw.y, (float)ha.y, acc);
#endif
}
__device__ __forceinline__ int dot4i(u32 w, u32 a, int acc) {
#ifdef HAS_SDOT4
  return __builtin_amdgcn_sdot4((int)w, (int)a, acc, false);
#else
  acc += (((int)(w << 24)) >> 24) * (((int)(a << 24)) >> 24);
  acc += (((int)(w << 16)) >> 24) * (((int)(a << 16)) >> 24);
  acc += (((int)(w << 8))  >> 24) * (((int)(a << 8))  >> 24);
  acc += (((int)w) >> 24)         * (((int)a) >> 24);
  return acc;
#endif
}
__device__ __forceinline__ u32 packf16(float x, float y) {
  half2v h; h.x = (_Float16)x; h.y = (_Float16)y;
  return __builtin_bit_cast(u32, h);
}

// ---- ws layout (bytes, 256-aligned) ----
#define O_WZX  256                       // f16 pairs, x-part of Wz: 32*2048 u32
#define O_WZ8  (O_WZX + 262144)          // i8 quads, h-part of Wz: 128*2048 u32
#define O_SWZ  (O_WZ8 + 1048576)         // per-output scale (s/127): f32[2048]
#define O_BBP  (O_SWZ + 8192)            // bb f16 pairs: 288*128 u32
#define O_FFP  (O_BBP + 147456)          // ff f16 pairs: 4*64*512 u32
#define O_BIF  (O_FFP + 524288)          // bi f32[2048]
#define O_FFB  (O_BIF + 8192)            // ff biases f32[4*512]
#define O_BBBF (O_FFB + 8192)            // bbb f32[128]
#define O_HWP  (O_BBBF + 512)            // head pairs u32[512]
#define O_HBF  (O_HWP + 2048)            // hb f32[2]
#define WS_NEED ((u64)(O_HBF + 256))     // ~2.0 MB

// ---------------- dtype detection (validated rounds 3-7) ----------------
__global__ void detect_kernel(const u16* x, const u16* wi, const u16* wh, int* flag) {
  const int l = threadIdx.x;
  int cnt = (((x[2 * l] >> 7) & 0xFF) < 134)
          + (((wi[2 * l] >> 7) & 0xFF) < 134)
          + (((wh[2 * l] >> 7) & 0xFF) < 134);
#pragma unroll
  for (int off = 32; off > 0; off >>= 1) cnt += __shfl_down(cnt, off, 64);
  if (l == 0) *flag = (cnt >= 180) ? 1 : 0;
}

__device__ __forceinline__ float ldf(int f, const void* s, u32 i) {
  return f ? bf2f(((const u16*)s)[i]) : ((const float*)s)[i];
}

// ---- prep: Wz x-part f16 pairs (k2<32) ----
__global__ void pwzx_kernel(const void* Wi, const int* __restrict__ flag,
                            u32* __restrict__ wzx) {
  const int o = blockIdx.x * 256 + threadIdx.x;   // 0..2047
  const int k2 = blockIdx.y;                      // 0..31
  const int f = *flag;
  const u32 i = (u32)o * DI + 2 * k2;
  wzx[(u32)k2 * GZ + o] = packf16(ldf(f, Wi, i), ldf(f, Wi, i + 1));
}

// ---- prep: Wz h-part -> i8 with per-output-row scale ----
__global__ void qwz_kernel(const void* Wh, const int* __restrict__ flag,
                           u32* __restrict__ wz8, float* __restrict__ swz) {
  const int o = blockIdx.x;        // 0..2047
  const int l = threadIdx.x;       // 0..63
  const int f = *flag;
  float w[8]; float mx = 0.f;
#pragma unroll
  for (int qq = 0; qq < 2; ++qq) {
    const int q = l + 64 * qq;
#pragma unroll
    for (int e = 0; e < 4; ++e) {
      const float v = ldf(f, Wh, (u32)o * DH + 4 * q + e);
      w[qq * 4 + e] = v; mx = fmaxf(mx, fabsf(v));
    }
  }
#pragma unroll
  for (int off = 32; off > 0; off >>= 1) mx = fmaxf(mx, __shfl_xor(mx, off, 64));
  mx = fmaxf(mx, 1e-20f);
  const float inv = 127.f / mx;
  if (l == 0) swz[o] = mx / (127.f * 127.f);  // weight scale x activation scale
#pragma unroll
  for (int qq = 0; qq < 2; ++qq) {
    const int q = l + 64 * qq;
    u32 p = 0;
#pragma unroll
    for (int e = 0; e < 4; ++e) {
      int b = (int)rintf(w[qq * 4 + e] * inv);
      b = b > 127 ? 127 : (b < -127 ? -127 : b);
      p |= ((u32)(b & 0xff)) << (8 * e);
    }
    wz8[(u32)q * GZ + o] = p;
  }
}

// ---- prep: bb / ff f16 pair transposes (validated rounds 5-7) ----
__global__ void pbb_kernel(const void* bb, const int* __restrict__ flag,
                           u32* __restrict__ bbp) {
  const int m = threadIdx.x;
  const int k2 = blockIdx.x;
  const int f = *flag;
  const u32 i = (u32)m * KZ + 2 * k2;
  bbp[(u32)k2 * DB + m] = packf16(ldf(f, bb, i), ldf(f, bb, i + 1));
}
__global__ void pff_kernel(const void* f1, const void* f2, const void* ta,
                           const void* tb, const int* __restrict__ flag,
                           u32* __restrict__ ffp) {
  const int o = blockIdx.x * 256 + threadIdx.x;
  const int k2 = blockIdx.y;
  const int mat = blockIdx.z;
  const void* s = (mat == 0) ? f1 : (mat == 1) ? f2 : (mat == 2) ? ta : tb;
  const int f = *flag;
  const u32 i = (u32)o * DB + 2 * k2;
  ffp[((u32)mat * 64 + k2) * DH + o] = packf16(ldf(f, s, i), ldf(f, s, i + 1));
}
__global__ void psmall_kernel(const void* bi_s, const void* f1b_s, const void* f2b_s,
                              const void* tab_s, const void* tbb_s, const void* bbb_s,
                              const void* hw_s, const void* hb_s,
                              const int* __restrict__ flag,
                              float* __restrict__ bif, float* __restrict__ ffb,
                              float* __restrict__ bbbf, u32* __restrict__ hwp,
                              float* __restrict__ hbf) {
  const int f = *flag;
  for (int i = threadIdx.x; i < 2048; i += 1024) {
    bif[i] = ldf(f, bi_s, i);
    if (i < 512) {
      ffb[i]        = ldf(f, f1b_s, i);
      ffb[512 + i]  = ldf(f, f2b_s, i);
      ffb[1024 + i] = ldf(f, tab_s, i);
      ffb[1536 + i] = ldf(f, tbb_s, i);
      const int w = i >> 8, pr = i & 255;
      hwp[i] = packf16(ldf(f, hw_s, w * DH + 2 * pr), ldf(f, hw_s, w * DH + 2 * pr + 1));
    }
    if (i < 128) bbbf[i] = ldf(f, bbb_s, i);
    if (i < 2)   hbf[i] = ldf(f, hb_s, i);
  }
}

// ---------------- main scan: r7 structure, Wh stream in i8 (sdot4) ----------------
__global__ __launch_bounds__(1024, 1)
void scan8(const void* __restrict__ xraw, const int* __restrict__ flagp,
           const u32* __restrict__ wzx, const u32* __restrict__ wz8,
           const float* __restrict__ swz,
           const u32* __restrict__ bbp, const u32* __restrict__ ffp,
           const float* __restrict__ bif, const float* __restrict__ ffbv,
           const float* __restrict__ bbbf, const u32* __restrict__ hwp,
           const float* __restrict__ hbf, float* __restrict__ out)
{
  __shared__ __align__(16) u32   xf16q[64];        // x(t) f16 pairs [k2][row]
  __shared__ __align__(16) u32   ah8q[256];        // h(t-1) i8 quads [k4][row]
  __shared__ __align__(16) u32   hf16[512];        // h(t) f16 pairs [u][row] (head)
  __shared__ __align__(16) u32   vcat2u[288 * 2];  // [x|h_lstm] f16 pairs (bb input)
  __shared__ __align__(16) float zred[2 * 2 * GZ]; // Z partials, 32 KB
  __shared__ __align__(16) float bbred[8 * 2 * DB];
  __shared__ __align__(16) u32   Fpk2u[64 * 2];
  __shared__ __align__(16) float zff[4 * 2 * DH];

  const int j = threadIdx.x;
  const int b = blockIdx.x;          // 0..63; rows 2b, 2b+1
  const int bf16in = *flagp;

  const int zs = j >> 9, zp = j & 511;          // Z: 2 slices x 512 output-quads
  const int bs = j >> 7, bm = j & 127;          // bb: 8 slices x 128 outputs
  const int fmat = j >> 8, fp = j & 255;        // ff: 4 mats x 256 out-pairs
  const int grow = j >> 8, gup = j & 255;       // gates/combine (j<512)
  const int frow = j >> 6, fk2 = j & 63;        // F pack (j<128)
  const int hrow = j >> 7, hw_ = (j >> 6) & 1, hl = j & 63;  // head (j<256)

  float2 bgi, bgg, bgf, bgo, cbf1, cbf2, cbta, cbtb;
  float c0 = 0.f, c1 = 0.f;
  if (j < 512) {
    bgi  = *(const float2*)(bif  + 0 * DH + 2 * gup);
    bgg  = *(const float2*)(bif  + 1 * DH + 2 * gup);
    bgf  = *(const float2*)(bif  + 2 * DH + 2 * gup);
    bgo  = *(const float2*)(bif  + 3 * DH + 2 * gup);
    cbf1 = *(const float2*)(ffbv + 0 * DH + 2 * gup);
    cbf2 = *(const float2*)(ffbv + 1 * DH + 2 * gup);
    cbta = *(const float2*)(ffbv + 2 * DH + 2 * gup);
    cbtb = *(const float2*)(ffbv + 3 * DH + 2 * gup);
  }
  float bbr0 = 0.f, bbr1 = 0.f;
  if (j < 128) { bbr0 = bbbf[2 * fk2]; bbr1 = bbbf[2 * fk2 + 1]; }
  u32 hwreg[4]; float hbr = 0.f;
  if (j < 256) {
#pragma unroll
    for (int i = 0; i < 4; ++i) hwreg[i] = hwp[hw_ * 256 + hl + 64 * i];
    hbr = hbf[hw_];
  }
  const float4 zsc = *(const float4*)(swz + 4 * zp);   // h-part scales, hoisted

  // h0 = 0 (both rows); stage x(t=0)
  if (j < 512) { hf16[j] = 0u; if (j < 256) ah8q[j] = 0u; }
  if (j < 64) {
    const int xr = j >> 5, xk = j & 31;
    const size_t xi = ((size_t)(2 * b + xr) * TT + 0) * 32 + xk;
    u32 pk;
    if (bf16in) {
      const u32 w = ((const u32*)xraw)[xi];
      pk = packf16(bf2f((u16)(w & 0xffffu)), bf2f((u16)(w >> 16)));
    } else {
      const float2 v = ((const float2*)xraw)[xi];
      pk = packf16(v.x, v.y);
    }
    xf16q[xk * 2 + xr] = pk;
  }
  __syncthreads();

  for (int t = 0; t < TT; ++t) {
    // copy x(t) into vcat (bb input) — runs alongside Z reads (read/read OK)
    if (j < 64) vcat2u[j] = xf16q[j];

    // ---- Z: x-part f16 dot2 + h-part i8 sdot4; thread owns outputs 4zp..4zp+3 ----
    {
      float f0 = 0, f1 = 0, f2 = 0, f3 = 0, f4 = 0, f5 = 0, f6 = 0, f7 = 0;
      const u32* wpx = wzx + (size_t)(zs * 16) * GZ + 4 * zp;
      const uint2* xp = (const uint2*)xf16q + zs * 16;
#pragma unroll
      for (int k2 = 0; k2 < 16; ++k2) {
        const uint4 w = *(const uint4*)wpx; wpx += GZ;
        const uint2 a = xp[k2];
        f0 = dot2p(w.x, a.x, f0); f1 = dot2p(w.y, a.x, f1);
        f2 = dot2p(w.z, a.x, f2); f3 = dot2p(w.w, a.x, f3);
        f4 = dot2p(w.x, a.y, f4); f5 = dot2p(w.y, a.y, f5);
        f6 = dot2p(w.z, a.y, f6); f7 = dot2p(w.w, a.y, f7);
      }
      int i0 = 0, i1 = 0, i2 = 0, i3 = 0, i4 = 0, i5 = 0, i6 = 0, i7 = 0;
      const u32* wph = wz8 + (size_t)(zs * 64) * GZ + 4 * zp;
      const uint2* hp = (const uint2*)ah8q + zs * 64;
#pragma unroll 8
      for (int k4 = 0; k4 < 64; ++k4) {
        const uint4 w = *(const uint4*)wph; wph += GZ;
        const uint2 a = hp[k4];
        i0 = dot4i(w.x, a.x, i0); i1 = dot4i(w.y, a.x, i1);
        i2 = dot4i(w.z, a.x, i2); i3 = dot4i(w.w, a.x, i3);
        i4 = dot4i(w.x, a.y, i4); i5 = dot4i(w.y, a.y, i5);
        i6 = dot4i(w.z, a.y, i6); i7 = dot4i(w.w, a.y, i7);
      }
      *(float4*)(zred + (zs * 2 + 0) * GZ + 4 * zp) =
          make_float4(f0 + zsc.x * (float)i0, f1 + zsc.y * (float)i1,
                      f2 + zsc.z * (float)i2, f3 + zsc.w * (float)i3);
      *(float4*)(zred + (zs * 2 + 1) * GZ + 4 * zp) =
          make_float4(f4 + zsc.x * (float)i4, f5 + zsc.y * (float)i5,
                      f6 + zsc.z * (float)i6, f7 + zsc.w * (float)i7);
    }
    __syncthreads();                                   // (1) zred ready

    // ---- LSTM gates ----
    if (j < 512) {
      float2 zi = bgi, zg = bgg, zf = bgf, zo = bgo;
#pragma unroll
      for (int sl = 0; sl < 2; ++sl) {
        const float* zr = zred + (sl * 2 + grow) * GZ + 2 * gup;
        { const float2 v = *(const float2*)(zr);        zi.x += v.x; zi.y += v.y; }
        { const float2 v = *(const float2*)(zr + 512);  zg.x += v.x; zg.y += v.y; }
        { const float2 v = *(const float2*)(zr + 1024); zf.x += v.x; zf.y += v.y; }
        { const float2 v = *(const float2*)(zr + 1536); zo.x += v.x; zo.y += v.y; }
      }
      c0 = fmaf(c0, fsig(zf.x + 1.f), ftanh(zi.x) * fsig(zg.x));
      c1 = fmaf(c1, fsig(zf.y + 1.f), ftanh(zi.y) * fsig(zg.y));
      vcat2u[(32 + gup) * 2 + grow] = packf16(ftanh(c0) * fsig(zo.x),
                                              ftanh(c1) * fsig(zo.y));
    }
    __syncthreads();                                   // (2) h_lstm ready

    // ---- backbone partials (f16, weight reused for both rows) ----
    {
      float a0 = 0.f, a1 = 0.f;
      const u32* bp = bbp + (size_t)(bs * 36) * DB + bm;
      const uint2* vp = (const uint2*)vcat2u + bs * 36;
#pragma unroll 6
      for (int q = 0; q < 36; ++q) {
        const u32 w = bp[(size_t)q * DB];
        const uint2 a = vp[q];
        a0 = dot2p(w, a.x, a0);
        a1 = dot2p(w, a.y, a1);
      }
      bbred[(bs * 2 + 0) * DB + bm] = a0;
      bbred[(bs * 2 + 1) * DB + bm] = a1;
    }
    __syncthreads();                                   // (3) bb partials

    if (j < 128) {
      float r0 = bbr0, r1 = bbr1;
#pragma unroll
      for (int sl = 0; sl < 8; ++sl) {
        const float2 v = *(const float2*)(bbred + (sl * 2 + frow) * DB + 2 * fk2);
        r0 += v.x; r1 += v.y;
      }
      Fpk2u[fk2 * 2 + frow] = packf16(1.7159f * ftanh(0.666f * r0),
                                      1.7159f * ftanh(0.666f * r1));
    }
    __syncthreads();                                   // (4) F ready

    // ---- ff1/ff2/ta/tb (f16, weight reused for both rows) ----
    {
      float z00 = 0, z01 = 0, z10 = 0, z11 = 0;
      const u32* fpw = ffp + (size_t)(fmat * 64) * DH + 2 * fp;
      const uint2* Fp = (const uint2*)Fpk2u;
#pragma unroll 8
      for (int k2 = 0; k2 < 64; ++k2) {
        const uint2 w = *(const uint2*)fpw; fpw += DH;
        const uint2 a = Fp[k2];
        z00 = dot2p(w.x, a.x, z00); z01 = dot2p(w.x, a.y, z01);
        z10 = dot2p(w.y, a.x, z10); z11 = dot2p(w.y, a.y, z11);
      }
      *(float2*)(zff + (fmat * 2 + 0) * DH + 2 * fp) = make_float2(z00, z10);
      *(float2*)(zff + (fmat * 2 + 1) * DH + 2 * fp) = make_float2(z01, z11);
    }
    __syncthreads();                                   // (5) zff ready

    // ---- combine -> h_new (f16 + i8) || stage x(t+1) ----
    if (j < 512) {
      const float2 v1 = *(const float2*)(zff + (0 * 2 + grow) * DH + 2 * gup);
      const float2 v2 = *(const float2*)(zff + (1 * 2 + grow) * DH + 2 * gup);
      const float2 va = *(const float2*)(zff + (2 * 2 + grow) * DH + 2 * gup);
      const float2 vb = *(const float2*)(zff + (3 * 2 + grow) * DH + 2 * gup);
      const float z1x = v1.x + cbf1.x, z1y = v1.y + cbf1.y;
      const float z2x = v2.x + cbf2.x, z2y = v2.y + cbf2.y;
      const float zax = va.x + cbta.x, zay = va.y + cbta.y;
      const float zbx = vb.x + cbtb.x, zby = vb.y + cbtb.y;
      const float ti0 = fsig(zax + zbx), ti1 = fsig(zay + zby);
      const float hn0 = fmaf(ftanh(z1x), 1.f - ti0, ti0 * ftanh(z2x));
      const float hn1 = fmaf(ftanh(z1y), 1.f - ti1, ti1 * ftanh(z2y));
      hf16[gup * 2 + grow] = packf16(hn0, hn1);
      const int q0 = (int)rintf(hn0 * 127.f), q1 = (int)rintf(hn1 * 127.f);
      ((u16*)ah8q)[((gup >> 1) * 2 + grow) * 2 + (gup & 1)] =
          (u16)((q0 & 0xff) | ((q1 & 0xff) << 8));
      if (t == TT - 1) {
        float* lp = out + (size_t)NB * TT * 2 + (size_t)(2 * b + grow) * DH + 2 * gup;
        lp[0] = hn0; lp[1] = hn1;
      }
    } else if (j < 576 && t + 1 < TT) {
      const int xr = (j - 512) >> 5, xk = (j - 512) & 31;
      const size_t xi = ((size_t)(2 * b + xr) * TT + (t + 1)) * 32 + xk;
      u32 pk;
      if (bf16in) {
        const u32 w = ((const u32*)xraw)[xi];
        pk = packf16(bf2f((u16)(w & 0xffffu)), bf2f((u16)(w >> 16)));
      } else {
        const float2 v = ((const float2*)xraw)[xi];
        pk = packf16(v.x, v.y);
      }
      xf16q[xk * 2 + xr] = pk;
    }
    __syncthreads();                                   // (6) h_new + x(t+1) ready

    // ---- head: runs in the shadow of next Z ----
    if (j < 256) {
      float acc = 0.f;
#pragma unroll
      for (int i = 0; i < 4; ++i)
        acc = dot2p(hwreg[i], hf16[(hl + 64 * i) * 2 + hrow], acc);
#pragma unroll
      for (int off = 32; off > 0; off >>= 1) acc += __shfl_down(acc, off, 64);
      if (hl == 0) out[((size_t)(2 * b + hrow) * TT + t) * 2 + hw_] = acc + hbr;
    }
  }
}

// ---------------- fallback (round-3 verified, bf16 d_in, small ws) ----------------
__device__ __forceinline__ void fma8(float& acc, const uint4 u, const float* v) {
  union { u32 i; float f; } tt;
  tt.i = u.x << 16;          acc = fmaf(tt.f, v[0], acc);
  tt.i = u.x & 0xffff0000u;  acc = fmaf(tt.f, v[1], acc);
  tt.i = u.y << 16;          acc = fmaf(tt.f, v[2], acc);
  tt.i = u.y & 0xffff0000u;  acc = fmaf(tt.f, v[3], acc);
  tt.i = u.z << 16;          acc = fmaf(tt.f, v[4], acc);
  tt.i = u.z & 0xffff0000u;  acc = fmaf(tt.f, v[5], acc);
  tt.i = u.w << 16;          acc = fmaf(tt.f, v[6], acc);
  tt.i = u.w & 0xffff0000u;  acc = fmaf(tt.f, v[7], acc);
}
__global__ __launch_bounds__(256, 1)
void fb_scan(const u16* __restrict__ x,   const u16* __restrict__ Wi,
             const u16* __restrict__ bi,  const u16* __restrict__ Wh,
             const u16* __restrict__ bbW, const u16* __restrict__ bbb,
             const u16* __restrict__ f1W, const u16* __restrict__ f1b,
             const u16* __restrict__ f2W, const u16* __restrict__ f2b,
             const u16* __restrict__ taW, const u16* __restrict__ tab,
             const u16* __restrict__ tbW, const u16* __restrict__ tbb,
             const u16* __restrict__ hW,  const u16* __restrict__ hb,
             float* __restrict__ out)
{
  __shared__ __align__(16) float vcat[DI + DH];
  __shared__ __align__(16) float Fb2[DB];
  __shared__ __align__(16) float fpart[256];
  __shared__ __align__(16) float hprev[DH];
  const int j = threadIdx.x, b = blockIdx.x;
  const int u0 = j, u1 = j + 256;
  float bi_r[8];
#pragma unroll
  for (int k = 0; k < 8; ++k) bi_r[k] = bf2f(bi[j + 256 * k]);
  const float b_f1_0 = bf2f(f1b[u0]), b_f1_1 = bf2f(f1b[u1]);
  const float b_f2_0 = bf2f(f2b[u0]), b_f2_1 = bf2f(f2b[u1]);
  const float b_ta_0 = bf2f(tab[u0]), b_ta_1 = bf2f(tab[u1]);
  const float b_tb_0 = bf2f(tbb[u0]), b_tb_1 = bf2f(tbb[u1]);
  const float b_bb = (j < DB) ? bf2f(bbb[j]) : 0.f;
  float hwr[8]; float hbr = 0.f;
  if (j < 128) {
    const int w = j >> 6, l = j & 63;
#pragma unroll
    for (int q = 0; q < 8; ++q) hwr[q] = bf2f(hW[w * DH + q * 64 + l]);
    hbr = bf2f(hb[w]);
  }
  float c0 = 0.f, c1 = 0.f;
  hprev[u0] = 0.f; hprev[u1] = 0.f;
  const u16* xp = x + (size_t)b * TT * DI;
  __syncthreads();
  for (int t = 0; t < TT; ++t) {
    if (j < DI) vcat[j] = bf2f(xp[t * DI + j]);
    __syncthreads();
    float a[8];
#pragma unroll
    for (int k = 0; k < 8; ++k) a[k] = bi_r[k];
#pragma unroll
    for (int r = 0; r < 8; ++r) {
      const u16* wr = Wi + ((size_t)(j + 256 * r)) * DI;
      float acc = a[r];
#pragma unroll
      for (int kk = 0; kk < DI; kk += 8) fma8(acc, *(const uint4*)(wr + kk), vcat + kk);
      a[r] = acc;
    }
#pragma unroll 1
    for (int kb = 0; kb < DH; kb += 64) {
      float hreg[64];
#pragma unroll
      for (int q = 0; q < 16; ++q)
        *(float4*)(hreg + 4 * q) = *(const float4*)(hprev + kb + 4 * q);
#pragma unroll
      for (int r = 0; r < 8; ++r) {
        const u16* wr = Wh + ((size_t)(j + 256 * r)) * DH + kb;
        float acc = a[r];
#pragma unroll
        for (int cc = 0; cc < 8; ++cc) fma8(acc, *(const uint4*)(wr + 8 * cc), hreg + 8 * cc);
        a[r] = acc;
      }
    }
    {
      const float cn0 = fmaf(c0, fsig(a[4] + 1.f), ftanh(a[0]) * fsig(a[2]));
      const float cn1 = fmaf(c1, fsig(a[5] + 1.f), ftanh(a[1]) * fsig(a[3]));
      c0 = cn0; c1 = cn1;
      vcat[DI + u0] = ftanh(cn0) * fsig(a[6]);
      vcat[DI + u1] = ftanh(cn1) * fsig(a[7]);
    }
    __syncthreads();
    {
      const int mm = j & (DB - 1), pp = j >> 7;
      const u16* br = bbW + (size_t)mm * KZ + pp * 288;
      const float* vs = vcat + pp * 288;
      float s0 = 0.f, s1 = 0.f, s2v = 0.f, s3 = 0.f;
#pragma unroll
      for (int kk = 0; kk < 288; kk += 32) {
        fma8(s0, *(const uint4*)(br + kk), vs + kk);
        fma8(s1, *(const uint4*)(br + kk + 8), vs + kk + 8);
        fma8(s2v, *(const uint4*)(br + kk + 16), vs + kk + 16);
        fma8(s3, *(const uint4*)(br + kk + 24), vs + kk + 24);
      }
      fpart[j] = (s0 + s1) + (s2v + s3);
    }
    __syncthreads();
    if (j < DB) Fb2[j] = 1.7159f * ftanh(0.666f * (b_bb + fpart[j] + fpart[j + DB]));
    __syncthreads();
    {
      float Fr[DB];
#pragma unroll
      for (int q = 0; q < 32; ++q) *(float4*)(Fr + 4 * q) = *(const float4*)(Fb2 + 4 * q);
      const u16* rp[8] = {
        f1W + (size_t)u0 * DB, f1W + (size_t)u1 * DB,
        f2W + (size_t)u0 * DB, f2W + (size_t)u1 * DB,
        taW + (size_t)u0 * DB, taW + (size_t)u1 * DB,
        tbW + (size_t)u0 * DB, tbW + (size_t)u1 * DB };
      float sacc[8] = { b_f1_0, b_f1_1, b_f2_0, b_f2_1, b_ta_0, b_ta_1, b_tb_0, b_tb_1 };
#pragma unroll
      for (int rr = 0; rr < 8; ++rr) {
        float acc = sacc[rr];
        const u16* r = rp[rr];
#pragma unroll
        for (int kk = 0; kk < DB; kk += 8) fma8(acc, *(const uint4*)(r + kk), Fr + kk);
        sacc[rr] = acc;
      }
      const float ti0 = fsig(sacc[4] + sacc[6]);
      const float ti1 = fsig(sacc[5] + sacc[7]);
      hprev[u0] = fmaf(ftanh(sacc[0]), 1.f - ti0, ti0 * ftanh(sacc[2]));
      hprev[u1] = fmaf(ftanh(sacc[1]), 1.f - ti1, ti1 * ftanh(sacc[3]));
    }
    __syncthreads();
    if (j < 128) {
      const int l = j & 63;
      float acc = 0.f;
#pragma unroll
      for (int q = 0; q < 8; ++q) acc = fmaf(hprev[q * 64 + l], hwr[q], acc);
#pragma unroll
      for (int off = 32; off > 0; off >>= 1) acc += __shfl_down(acc, off, 64);
      if (l == 0) out[((size_t)b * TT + t) * 2 + (j >> 6)] = acc + hbr;
    }
  }
  out[(size_t)NB * TT * 2 + (size_t)b * DH + u0] = hprev[u0];
  out[(size_t)NB * TT * 2 + (size_t)b * DH + u1] = hprev[u1];
}

extern "C" void kernel_launch(void* const* d_in, const int* in_sizes, int n_in,
                              void* d_out, int out_size, void* d_ws, size_t ws_size,
                              hipStream_t stream) {
  (void)in_sizes; (void)n_in; (void)out_size;

  if (ws_size >= WS_NEED) {
    char* ws = (char*)d_ws;
    int* flag = (int*)ws;
    detect_kernel<<<dim3(1), dim3(64), 0, stream>>>(
        (const u16*)d_in[0], (const u16*)d_in[1], (const u16*)d_in[3], flag);
    pwzx_kernel<<<dim3(8, 32), dim3(256), 0, stream>>>(d_in[1], flag, (u32*)(ws + O_WZX));
    qwz_kernel<<<dim3(2048), dim3(64), 0, stream>>>(d_in[3], flag,
                                                    (u32*)(ws + O_WZ8), (float*)(ws + O_SWZ));
    pbb_kernel<<<dim3(288), dim3(128), 0, stream>>>(d_in[4], flag, (u32*)(ws + O_BBP));
    pff_kernel<<<dim3(2, 64, 4), dim3(256), 0, stream>>>(d_in[6], d_in[8], d_in[10],
                                                         d_in[12], flag, (u32*)(ws + O_FFP));
    psmall_kernel<<<dim3(1), dim3(1024), 0, stream>>>(
        d_in[2], d_in[7], d_in[9], d_in[11], d_in[13], d_in[5], d_in[14], d_in[15],
        flag, (float*)(ws + O_BIF), (float*)(ws + O_FFB), (float*)(ws + O_BBBF),
        (u32*)(ws + O_HWP), (float*)(ws + O_HBF));

    scan8<<<dim3(64), dim3(1024), 0, stream>>>(
        d_in[0], flag,
        (const u32*)(ws + O_WZX), (const u32*)(ws + O_WZ8), (const float*)(ws + O_SWZ),
        (const u32*)(ws + O_BBP), (const u32*)(ws + O_FFP),
        (const float*)(ws + O_BIF), (const float*)(ws + O_FFB),
        (const float*)(ws + O_BBBF), (const u32*)(ws + O_HWP),
        (const float*)(ws + O_HBF), (float*)d_out);
  } else {
    fb_scan<<<dim3(NB), dim3(256), 0, stream>>>(
        (const u16*)d_in[0],  (const u16*)d_in[1],  (const u16*)d_in[2],
        (const u16*)d_in[3],  (const u16*)d_in[4],  (const u16*)d_in[5],
        (const u16*)d_in[6],  (const u16*)d_in[7],  (const u16*)d_in[8],
        (const u16*)d_in[9],  (const u16*)d_in[10], (const u16*)d_in[11],
        (const u16*)d_in[12], (const u16*)d_in[13], (const u16*)d_in[14],
        (const u16*)d_in[15], (float*)d_out);
  }
}

// Round 9
// 21001.543 us; speedup vs baseline: 1.9545x; 1.1293x over previous
//
#include <hip/hip_runtime.h>

#define NB 128
#define TT 1024
#define DI 64
#define DH 512
#define DB 128
#define GZ 2048
#define KZ 576

typedef unsigned short u16;
typedef unsigned int u32;
typedef unsigned long long u64;

#if defined(__has_builtin)
#if __has_builtin(__builtin_amdgcn_fdot2)
#define HAS_FDOT2 1
#endif
#if __has_builtin(__builtin_amdgcn_sdot4)
#define HAS_SDOT4 1
#endif
#endif

typedef _Float16 half2v __attribute__((ext_vector_type(2)));

__device__ __forceinline__ float bf2f(u16 u) {
  union { u32 i; float f; } v; v.i = ((u32)u) << 16; return v.f;
}
__device__ __forceinline__ float fsig(float x) {
  return __builtin_amdgcn_rcpf(1.f + __expf(-x));
}
__device__ __forceinline__ float ftanh(float x) {
  return 1.f - 2.f * __builtin_amdgcn_rcpf(__expf(2.f * x) + 1.f);
}
__device__ __forceinline__ float dot2p(u32 w, u32 a, float acc) {
#ifdef HAS_FDOT2
  return __builtin_amdgcn_fdot2(__builtin_bit_cast(half2v, w),
                                __builtin_bit_cast(half2v, a), acc, false);
#else
  half2v hw = __builtin_bit_cast(half2v, w), ha = __builtin_bit_cast(half2v, a);
  acc = fmaf((float)hw.x, (float)ha.x, acc);
  return fmaf((float)hw.y, (float)ha.y, acc);
#endif
}
__device__ __forceinline__ int dot4i(u32 w, u32 a, int acc) {
#ifdef HAS_SDOT4
  return __builtin_amdgcn_sdot4((int)w, (int)a, acc, false);
#else
  acc += (((int)(w << 24)) >> 24) * (((int)(a << 24)) >> 24);
  acc += (((int)(w << 16)) >> 24) * (((int)(a << 16)) >> 24);
  acc += (((int)(w << 8))  >> 24) * (((int)(a << 8))  >> 24);
  acc += (((int)w) >> 24)         * (((int)a) >> 24);
  return acc;
#endif
}
__device__ __forceinline__ u32 packf16(float x, float y) {
  half2v h; h.x = (_Float16)x; h.y = (_Float16)y;
  return __builtin_bit_cast(u32, h);
}

// ---- ws layout (bytes, 256-aligned) ----
#define O_WZX  256                       // f16 pairs, x-part of Wz: 32*2048 u32
#define O_WZ8  (O_WZX + 262144)          // i8 quads, h-part of Wz: 128*2048 u32
#define O_SWZ  (O_WZ8 + 1048576)         // Wh scales (s/127^2): f32[2048]
#define O_BB8  (O_SWZ + 8192)            // bb i8 quads: 144*128 u32
#define O_SBB  (O_BB8 + 73728)           // bb weight scales: f32[128]
#define O_FF8  (O_SBB + 512)             // ff i8 quads: 4*32*512 u32
#define O_SFF  (O_FF8 + 262144)          // ff scales (w*Fq): f32[2048]
#define O_BIF  (O_SFF + 8192)            // bi f32[2048]
#define O_FFB  (O_BIF + 8192)            // ff biases f32[4*512]
#define O_BBBF (O_FFB + 8192)            // bbb f32[128]
#define O_HWP  (O_BBBF + 512)            // head pairs u32[512]
#define O_HBF  (O_HWP + 2048)            // hb f32[2]
#define WS_NEED ((u64)(O_HBF + 256))     // ~1.68 MB

// ---------------- dtype detection (validated rounds 3-8) ----------------
__global__ void detect_kernel(const u16* x, const u16* wi, const u16* wh, int* flag) {
  const int l = threadIdx.x;
  int cnt = (((x[2 * l] >> 7) & 0xFF) < 134)
          + (((wi[2 * l] >> 7) & 0xFF) < 134)
          + (((wh[2 * l] >> 7) & 0xFF) < 134);
#pragma unroll
  for (int off = 32; off > 0; off >>= 1) cnt += __shfl_down(cnt, off, 64);
  if (l == 0) *flag = (cnt >= 180) ? 1 : 0;
}

__device__ __forceinline__ float ldf(int f, const void* s, u32 i) {
  return f ? bf2f(((const u16*)s)[i]) : ((const float*)s)[i];
}

// ---- prep: Wz x-part f16 pairs ----
__global__ void pwzx_kernel(const void* Wi, const int* __restrict__ flag,
                            u32* __restrict__ wzx) {
  const int o = blockIdx.x * 256 + threadIdx.x;
  const int k2 = blockIdx.y;
  const int f = *flag;
  const u32 i = (u32)o * DI + 2 * k2;
  wzx[(u32)k2 * GZ + o] = packf16(ldf(f, Wi, i), ldf(f, Wi, i + 1));
}

// ---- prep: Wz h-part -> i8 per-output-row scale (validated round 8) ----
__global__ void qwz_kernel(const void* Wh, const int* __restrict__ flag,
                           u32* __restrict__ wz8, float* __restrict__ swz) {
  const int o = blockIdx.x;
  const int l = threadIdx.x;
  const int f = *flag;
  float w[8]; float mx = 0.f;
#pragma unroll
  for (int qq = 0; qq < 2; ++qq) {
    const int q = l + 64 * qq;
#pragma unroll
    for (int e = 0; e < 4; ++e) {
      const float v = ldf(f, Wh, (u32)o * DH + 4 * q + e);
      w[qq * 4 + e] = v; mx = fmaxf(mx, fabsf(v));
    }
  }
#pragma unroll
  for (int off = 32; off > 0; off >>= 1) mx = fmaxf(mx, __shfl_xor(mx, off, 64));
  mx = fmaxf(mx, 1e-20f);
  const float inv = 127.f / mx;
  if (l == 0) swz[o] = mx / (127.f * 127.f);
#pragma unroll
  for (int qq = 0; qq < 2; ++qq) {
    const int q = l + 64 * qq;
    u32 p = 0;
#pragma unroll
    for (int e = 0; e < 4; ++e) {
      int b = (int)rintf(w[qq * 4 + e] * inv);
      b = b > 127 ? 127 : (b < -127 ? -127 : b);
      p |= ((u32)(b & 0xff)) << (8 * e);
    }
    wz8[(u32)q * GZ + o] = p;
  }
}

// ---- prep: backbone -> i8, per-output scale. block = output m, 64 threads ----
__global__ void qbb_kernel(const void* bb, const int* __restrict__ flag,
                           u32* __restrict__ bb8, float* __restrict__ sbb) {
  const int m = blockIdx.x;      // 0..127
  const int l = threadIdx.x;     // 0..63
  const int f = *flag;
  float mx = 0.f;
#pragma unroll
  for (int q = 0; q < 9; ++q)
    mx = fmaxf(mx, fabsf(ldf(f, bb, (u32)m * KZ + l + 64 * q)));
#pragma unroll
  for (int off = 32; off > 0; off >>= 1) mx = fmaxf(mx, __shfl_xor(mx, off, 64));
  mx = fmaxf(mx, 1e-20f);
  const float inv = 127.f / mx;
  if (l == 0) sbb[m] = mx / 127.f;   // weight dequant only; act scales applied in-kernel
  for (int k4 = l; k4 < 144; k4 += 64) {
    u32 p = 0;
#pragma unroll
    for (int e = 0; e < 4; ++e) {
      int b = (int)rintf(ldf(f, bb, (u32)m * KZ + 4 * k4 + e) * inv);
      b = b > 127 ? 127 : (b < -127 ? -127 : b);
      p |= ((u32)(b & 0xff)) << (8 * e);
    }
    bb8[(u32)k4 * DB + m] = p;
  }
}

// ---- prep: ff -> i8, per-(mat,output) scale folded with F-scale. block=(o,mat) ----
__global__ void qff_kernel(const void* f1, const void* f2, const void* ta,
                           const void* tb, const int* __restrict__ flag,
                           u32* __restrict__ ff8, float* __restrict__ sff) {
  const int o = blockIdx.x;      // 0..511
  const int mat = blockIdx.y;    // 0..3
  const int l = threadIdx.x;     // 0..31
  const void* s = (mat == 0) ? f1 : (mat == 1) ? f2 : (mat == 2) ? ta : tb;
  const int f = *flag;
  float w[4]; float mx = 0.f;
#pragma unroll
  for (int e = 0; e < 4; ++e) {
    w[e] = ldf(f, s, (u32)o * DB + 4 * l + e);
    mx = fmaxf(mx, fabsf(w[e]));
  }
#pragma unroll
  for (int off = 16; off > 0; off >>= 1) mx = fmaxf(mx, __shfl_xor(mx, off, 32));
  mx = fmaxf(mx, 1e-20f);
  const float inv = 127.f / mx;
  if (l == 0) sff[mat * DH + o] = (mx / 127.f) * (1.7159f / 127.f);  // w + F dequant
  u32 p = 0;
#pragma unroll
  for (int e = 0; e < 4; ++e) {
    int b = (int)rintf(w[e] * inv);
    b = b > 127 ? 127 : (b < -127 ? -127 : b);
    p |= ((u32)(b & 0xff)) << (8 * e);
  }
  ff8[((u32)mat * 32 + l) * DH + o] = p;
}

__global__ void psmall_kernel(const void* bi_s, const void* f1b_s, const void* f2b_s,
                              const void* tab_s, const void* tbb_s, const void* bbb_s,
                              const void* hw_s, const void* hb_s,
                              const int* __restrict__ flag,
                              float* __restrict__ bif, float* __restrict__ ffb,
                              float* __restrict__ bbbf, u32* __restrict__ hwp,
                              float* __restrict__ hbf) {
  const int f = *flag;
  for (int i = threadIdx.x; i < 2048; i += 1024) {
    bif[i] = ldf(f, bi_s, i);
    if (i < 512) {
      ffb[i]        = ldf(f, f1b_s, i);
      ffb[512 + i]  = ldf(f, f2b_s, i);
      ffb[1024 + i] = ldf(f, tab_s, i);
      ffb[1536 + i] = ldf(f, tbb_s, i);
      const int w = i >> 8, pr = i & 255;
      hwp[i] = packf16(ldf(f, hw_s, w * DH + 2 * pr), ldf(f, hw_s, w * DH + 2 * pr + 1));
    }
    if (i < 128) bbbf[i] = ldf(f, bbb_s, i);
    if (i < 2)   hbf[i] = ldf(f, hb_s, i);
  }
}

// ---------------- main scan: r8 structure; Wh+bb+ff all i8 ----------------
__global__ __launch_bounds__(1024, 1)
void scan9(const void* __restrict__ xraw, const int* __restrict__ flagp,
           const u32* __restrict__ wzx, const u32* __restrict__ wz8,
           const float* __restrict__ swz,
           const u32* __restrict__ bb8, const float* __restrict__ sbb,
           const u32* __restrict__ ff8, const float* __restrict__ sff,
           const float* __restrict__ bif, const float* __restrict__ ffbv,
           const float* __restrict__ bbbf, const u32* __restrict__ hwp,
           const float* __restrict__ hbf, float* __restrict__ out)
{
  __shared__ __align__(16) u32   xf16q[64];        // x(t) f16 pairs [k2][row]
  __shared__ __align__(16) u32   ah8q[256];        // h(t-1) i8 quads [k4][row] (Z in)
  __shared__ __align__(16) u32   hf16[512];        // h(t) f16 pairs [u][row] (head)
  __shared__ __align__(16) u32   vcat8[288];       // [x|h_lstm] i8 quads [k4][row]
  __shared__ __align__(16) float sxq[2];           // per-row x quant scale
  __shared__ __align__(16) float zred[2 * 2 * GZ]; // Z partials, 32 KB
  __shared__ __align__(16) float bbred[8 * 2 * DB];
  __shared__ __align__(16) u32   Fq8[64];          // F i8 quads [k4][row]
  __shared__ __align__(16) float zff[4 * 2 * DH];

  const int j = threadIdx.x;
  const int b = blockIdx.x;          // 0..63; rows 2b, 2b+1
  const int bf16in = *flagp;

  const int zs = j >> 9, zp = j & 511;          // Z: 2 slices x 512 output-quads
  const int bs = j >> 7, bm = j & 127;          // bb: 8 slices x 128 outputs
  const int fmat = j >> 8, fp = j & 255;        // ff: 4 mats x 256 out-pairs
  const int grow = j >> 8, gup = j & 255;       // gates/combine (j<512)
  const int frow = j >> 6, fk2 = j & 63;        // F pack (j<128)
  const int hrow = j >> 7, hw_ = (j >> 6) & 1, hl = j & 63;  // head (j<256)

  float2 bgi, bgg, bgf, bgo, cbf1, cbf2, cbta, cbtb;
  float c0 = 0.f, c1 = 0.f;
  if (j < 512) {
    bgi  = *(const float2*)(bif  + 0 * DH + 2 * gup);
    bgg  = *(const float2*)(bif  + 1 * DH + 2 * gup);
    bgf  = *(const float2*)(bif  + 2 * DH + 2 * gup);
    bgo  = *(const float2*)(bif  + 3 * DH + 2 * gup);
    cbf1 = *(const float2*)(ffbv + 0 * DH + 2 * gup);
    cbf2 = *(const float2*)(ffbv + 1 * DH + 2 * gup);
    cbta = *(const float2*)(ffbv + 2 * DH + 2 * gup);
    cbtb = *(const float2*)(ffbv + 3 * DH + 2 * gup);
  }
  float bbr0 = 0.f, bbr1 = 0.f;
  if (j < 128) { bbr0 = bbbf[2 * fk2]; bbr1 = bbbf[2 * fk2 + 1]; }
  u32 hwreg[4]; float hbr = 0.f;
  if (j < 256) {
#pragma unroll
    for (int i = 0; i < 4; ++i) hwreg[i] = hwp[hw_ * 256 + hl + 64 * i];
    hbr = hbf[hw_];
  }
  const float4 zsc = *(const float4*)(swz + 4 * zp);       // Wh scales
  const float sbbr = sbb[bm];                              // bb weight scale
  const float sf0 = sff[fmat * DH + 2 * fp];               // ff scales (w*F folded)
  const float sf1 = sff[fmat * DH + 2 * fp + 1];
  const float C127 = 1.f / 127.f;

  // ---- preamble: h0 = 0; stage x(0): f16 (Z), i8+scale (bb) ----
  if (j < 512) { hf16[j] = 0u; if (j < 256) ah8q[j] = 0u; }
  if (j >= 512 && j < 576) {
    const int i = j - 512, xr = i >> 5, k2 = i & 31;
    const size_t xi = ((size_t)(2 * b + xr) * TT + 0) * 32 + k2;
    float a, bb_;
    if (bf16in) {
      const u32 w = ((const u32*)xraw)[xi];
      a = bf2f((u16)(w & 0xffffu)); bb_ = bf2f((u16)(w >> 16));
    } else {
      const float2 v = ((const float2*)xraw)[xi];
      a = v.x; bb_ = v.y;
    }
    xf16q[k2 * 2 + xr] = packf16(a, bb_);
    float m = fmaxf(fabsf(a), fabsf(bb_));
#pragma unroll
    for (int off = 16; off > 0; off >>= 1) m = fmaxf(m, __shfl_xor(m, off, 32));
    m = fmaxf(m, 1e-20f);
    if (k2 == 0) sxq[xr] = m * C127;
    const float inv = 127.f / m;
    const int q0 = (int)rintf(a * inv), q1 = (int)rintf(bb_ * inv);
    ((u16*)vcat8)[((k2 >> 1) * 2 + xr) * 2 + (k2 & 1)] =
        (u16)((q0 & 0xff) | ((q1 & 0xff) << 8));
  }
  __syncthreads();

  for (int t = 0; t < TT; ++t) {
    // ---- Z: x-part f16 dot2 + h-part i8 sdot4 ----
    {
      float f0 = 0, f1 = 0, f2 = 0, f3 = 0, f4 = 0, f5 = 0, f6 = 0, f7 = 0;
      const u32* wpx = wzx + (size_t)(zs * 16) * GZ + 4 * zp;
      const uint2* xp = (const uint2*)xf16q + zs * 16;
#pragma unroll
      for (int k2 = 0; k2 < 16; ++k2) {
        const uint4 w = *(const uint4*)wpx; wpx += GZ;
        const uint2 a = xp[k2];
        f0 = dot2p(w.x, a.x, f0); f1 = dot2p(w.y, a.x, f1);
        f2 = dot2p(w.z, a.x, f2); f3 = dot2p(w.w, a.x, f3);
        f4 = dot2p(w.x, a.y, f4); f5 = dot2p(w.y, a.y, f5);
        f6 = dot2p(w.z, a.y, f6); f7 = dot2p(w.w, a.y, f7);
      }
      int i0 = 0, i1 = 0, i2 = 0, i3 = 0, i4 = 0, i5 = 0, i6 = 0, i7 = 0;
      const u32* wph = wz8 + (size_t)(zs * 64) * GZ + 4 * zp;
      const uint2* hp = (const uint2*)ah8q + zs * 64;
#pragma unroll 16
      for (int k4 = 0; k4 < 64; ++k4) {
        const uint4 w = *(const uint4*)wph; wph += GZ;
        const uint2 a = hp[k4];
        i0 = dot4i(w.x, a.x, i0); i1 = dot4i(w.y, a.x, i1);
        i2 = dot4i(w.z, a.x, i2); i3 = dot4i(w.w, a.x, i3);
        i4 = dot4i(w.x, a.y, i4); i5 = dot4i(w.y, a.y, i5);
        i6 = dot4i(w.z, a.y, i6); i7 = dot4i(w.w, a.y, i7);
      }
      *(float4*)(zred + (zs * 2 + 0) * GZ + 4 * zp) =
          make_float4(f0 + zsc.x * (float)i0, f1 + zsc.y * (float)i1,
                      f2 + zsc.z * (float)i2, f3 + zsc.w * (float)i3);
      *(float4*)(zred + (zs * 2 + 1) * GZ + 4 * zp) =
          make_float4(f4 + zsc.x * (float)i4, f5 + zsc.y * (float)i5,
                      f6 + zsc.z * (float)i6, f7 + zsc.w * (float)i7);
    }
    __syncthreads();                                   // (1) zred ready

    // ---- LSTM gates; h_lstm -> i8 into vcat8 ----
    if (j < 512) {
      float2 zi = bgi, zg = bgg, zf = bgf, zo = bgo;
#pragma unroll
      for (int sl = 0; sl < 2; ++sl) {
        const float* zr = zred + (sl * 2 + grow) * GZ + 2 * gup;
        { const float2 v = *(const float2*)(zr);        zi.x += v.x; zi.y += v.y; }
        { const float2 v = *(const float2*)(zr + 512);  zg.x += v.x; zg.y += v.y; }
        { const float2 v = *(const float2*)(zr + 1024); zf.x += v.x; zf.y += v.y; }
        { const float2 v = *(const float2*)(zr + 1536); zo.x += v.x; zo.y += v.y; }
      }
      c0 = fmaf(c0, fsig(zf.x + 1.f), ftanh(zi.x) * fsig(zg.x));
      c1 = fmaf(c1, fsig(zf.y + 1.f), ftanh(zi.y) * fsig(zg.y));
      const float hl0 = ftanh(c0) * fsig(zo.x);
      const float hl1 = ftanh(c1) * fsig(zo.y);
      const int q0 = (int)rintf(hl0 * 127.f), q1 = (int)rintf(hl1 * 127.f);
      ((u16*)vcat8)[((16 + (gup >> 1)) * 2 + grow) * 2 + (gup & 1)] =
          (u16)((q0 & 0xff) | ((q1 & 0xff) << 8));
    }
    __syncthreads();                                   // (2) h_lstm ready

    // ---- backbone partials: i8 sdot4, x/h scale split ----
    {
      int ax0 = 0, ax1 = 0, ah0 = 0, ah1 = 0;
      const u32* bp = bb8 + (size_t)(bs * 18) * DB + bm;
      const uint2* vp = (const uint2*)vcat8 + bs * 18;
#pragma unroll
      for (int q = 0; q < 18; ++q) {
        const u32 w = bp[(size_t)q * DB];
        const uint2 a = vp[q];
        if (bs * 18 + q < 16) {           // x segment (wave-uniform branch)
          ax0 = dot4i(w, a.x, ax0); ax1 = dot4i(w, a.y, ax1);
        } else {                          // h_lstm segment
          ah0 = dot4i(w, a.x, ah0); ah1 = dot4i(w, a.y, ah1);
        }
      }
      const float sx0 = sxq[0], sx1 = sxq[1];
      bbred[(bs * 2 + 0) * DB + bm] = sbbr * (sx0 * (float)ax0 + C127 * (float)ah0);
      bbred[(bs * 2 + 1) * DB + bm] = sbbr * (sx1 * (float)ax1 + C127 * (float)ah1);
    }
    __syncthreads();                                   // (3) bb partials

    // ---- F reduce + lecun_tanh -> i8 quads ----
    if (j < 128) {
      float r0 = bbr0, r1 = bbr1;
#pragma unroll
      for (int sl = 0; sl < 8; ++sl) {
        const float2 v = *(const float2*)(bbred + (sl * 2 + frow) * DB + 2 * fk2);
        r0 += v.x; r1 += v.y;
      }
      const float F0 = 1.7159f * ftanh(0.666f * r0);
      const float F1 = 1.7159f * ftanh(0.666f * r1);
      const int q0 = (int)rintf(F0 * (127.f / 1.7159f));
      const int q1 = (int)rintf(F1 * (127.f / 1.7159f));
      ((u16*)Fq8)[((fk2 >> 1) * 2 + frow) * 2 + (fk2 & 1)] =
          (u16)((q0 & 0xff) | ((q1 & 0xff) << 8));
    }
    __syncthreads();                                   // (4) F ready

    // ---- ff1/ff2/ta/tb: i8 sdot4, weight uint2 reused for both rows ----
    {
      int a00 = 0, a01 = 0, a10 = 0, a11 = 0;
      const u32* fpw = ff8 + (size_t)(fmat * 32) * DH + 2 * fp;
      const uint2* Fp = (const uint2*)Fq8;
#pragma unroll 8
      for (int k4 = 0; k4 < 32; ++k4) {
        const uint2 w = *(const uint2*)fpw; fpw += DH;
        const uint2 a = Fp[k4];
        a00 = dot4i(w.x, a.x, a00); a01 = dot4i(w.x, a.y, a01);
        a10 = dot4i(w.y, a.x, a10); a11 = dot4i(w.y, a.y, a11);
      }
      *(float2*)(zff + (fmat * 2 + 0) * DH + 2 * fp) =
          make_float2(sf0 * (float)a00, sf1 * (float)a10);
      *(float2*)(zff + (fmat * 2 + 1) * DH + 2 * fp) =
          make_float2(sf0 * (float)a01, sf1 * (float)a11);
    }
    __syncthreads();                                   // (5) zff ready

    // ---- combine -> h_new (f16 + i8) || stage x(t+1) (f16 + i8 + scale) ----
    if (j < 512) {
      const float2 v1 = *(const float2*)(zff + (0 * 2 + grow) * DH + 2 * gup);
      const float2 v2 = *(const float2*)(zff + (1 * 2 + grow) * DH + 2 * gup);
      const float2 va = *(const float2*)(zff + (2 * 2 + grow) * DH + 2 * gup);
      const float2 vb = *(const float2*)(zff + (3 * 2 + grow) * DH + 2 * gup);
      const float z1x = v1.x + cbf1.x, z1y = v1.y + cbf1.y;
      const float z2x = v2.x + cbf2.x, z2y = v2.y + cbf2.y;
      const float zax = va.x + cbta.x, zay = va.y + cbta.y;
      const float zbx = vb.x + cbtb.x, zby = vb.y + cbtb.y;
      const float ti0 = fsig(zax + zbx), ti1 = fsig(zay + zby);
      const float hn0 = fmaf(ftanh(z1x), 1.f - ti0, ti0 * ftanh(z2x));
      const float hn1 = fmaf(ftanh(z1y), 1.f - ti1, ti1 * ftanh(z2y));
      hf16[gup * 2 + grow] = packf16(hn0, hn1);
      const int q0 = (int)rintf(hn0 * 127.f), q1 = (int)rintf(hn1 * 127.f);
      ((u16*)ah8q)[((gup >> 1) * 2 + grow) * 2 + (gup & 1)] =
          (u16)((q0 & 0xff) | ((q1 & 0xff) << 8));
      if (t == TT - 1) {
        float* lp = out + (size_t)NB * TT * 2 + (size_t)(2 * b + grow) * DH + 2 * gup;
        lp[0] = hn0; lp[1] = hn1;
      }
    } else if (j < 576 && t + 1 < TT) {
      const int i = j - 512, xr = i >> 5, k2 = i & 31;
      const size_t xi = ((size_t)(2 * b + xr) * TT + (t + 1)) * 32 + k2;
      float a, bb_;
      if (bf16in) {
        const u32 w = ((const u32*)xraw)[xi];
        a = bf2f((u16)(w & 0xffffu)); bb_ = bf2f((u16)(w >> 16));
      } else {
        const float2 v = ((const float2*)xraw)[xi];
        a = v.x; bb_ = v.y;
      }
      xf16q[k2 * 2 + xr] = packf16(a, bb_);
      float m = fmaxf(fabsf(a), fabsf(bb_));
#pragma unroll
      for (int off = 16; off > 0; off >>= 1) m = fmaxf(m, __shfl_xor(m, off, 32));
      m = fmaxf(m, 1e-20f);
      if (k2 == 0) sxq[xr] = m * C127;
      const float inv = 127.f / m;
      const int q0 = (int)rintf(a * inv), q1 = (int)rintf(bb_ * inv);
      ((u16*)vcat8)[((k2 >> 1) * 2 + xr) * 2 + (k2 & 1)] =
          (u16)((q0 & 0xff) | ((q1 & 0xff) << 8));
    }
    __syncthreads();                                   // (6) h_new + x(t+1) ready

    // ---- head: runs in the shadow of next Z ----
    if (j < 256) {
      float acc = 0.f;
#pragma unroll
      for (int i = 0; i < 4; ++i)
        acc = dot2p(hwreg[i], hf16[(hl + 64 * i) * 2 + hrow], acc);
#pragma unroll
      for (int off = 32; off > 0; off >>= 1) acc += __shfl_down(acc, off, 64);
      if (hl == 0) out[((size_t)(2 * b + hrow) * TT + t) * 2 + hw_] = acc + hbr;
    }
  }
}

// ---------------- fallback (round-3 verified, bf16 d_in, small ws) ----------------
__device__ __forceinline__ void fma8(float& acc, const uint4 u, const float* v) {
  union { u32 i; float f; } tt;
  tt.i = u.x << 16;          acc = fmaf(tt.f, v[0], acc);
  tt.i = u.x & 0xffff0000u;  acc = fmaf(tt.f, v[1], acc);
  tt.i = u.y << 16;          acc = fmaf(tt.f, v[2], acc);
  tt.i = u.y & 0xffff0000u;  acc = fmaf(tt.f, v[3], acc);
  tt.i = u.z << 16;          acc = fmaf(tt.f, v[4], acc);
  tt.i = u.z & 0xffff0000u;  acc = fmaf(tt.f, v[5], acc);
  tt.i = u.w << 16;          acc = fmaf(tt.f, v[6], acc);
  tt.i = u.w & 0xffff0000u;  acc = fmaf(tt.f, v[7], acc);
}
__global__ __launch_bounds__(256, 1)
void fb_scan(const u16* __restrict__ x,   const u16* __restrict__ Wi,
             const u16* __restrict__ bi,  const u16* __restrict__ Wh,
             const u16* __restrict__ bbW, const u16* __restrict__ bbb,
             const u16* __restrict__ f1W, const u16* __restrict__ f1b,
             const u16* __restrict__ f2W, const u16* __restrict__ f2b,
             const u16* __restrict__ taW, const u16* __restrict__ tab,
             const u16* __restrict__ tbW, const u16* __restrict__ tbb,
             const u16* __restrict__ hW,  const u16* __restrict__ hb,
             float* __restrict__ out)
{
  __shared__ __align__(16) float vcat[DI + DH];
  __shared__ __align__(16) float Fb2[DB];
  __shared__ __align__(16) float fpart[256];
  __shared__ __align__(16) float hprev[DH];
  const int j = threadIdx.x, b = blockIdx.x;
  const int u0 = j, u1 = j + 256;
  float bi_r[8];
#pragma unroll
  for (int k = 0; k < 8; ++k) bi_r[k] = bf2f(bi[j + 256 * k]);
  const float b_f1_0 = bf2f(f1b[u0]), b_f1_1 = bf2f(f1b[u1]);
  const float b_f2_0 = bf2f(f2b[u0]), b_f2_1 = bf2f(f2b[u1]);
  const float b_ta_0 = bf2f(tab[u0]), b_ta_1 = bf2f(tab[u1]);
  const float b_tb_0 = bf2f(tbb[u0]), b_tb_1 = bf2f(tbb[u1]);
  const float b_bb = (j < DB) ? bf2f(bbb[j]) : 0.f;
  float hwr[8]; float hbr = 0.f;
  if (j < 128) {
    const int w = j >> 6, l = j & 63;
#pragma unroll
    for (int q = 0; q < 8; ++q) hwr[q] = bf2f(hW[w * DH + q * 64 + l]);
    hbr = bf2f(hb[w]);
  }
  float c0 = 0.f, c1 = 0.f;
  hprev[u0] = 0.f; hprev[u1] = 0.f;
  const u16* xp = x + (size_t)b * TT * DI;
  __syncthreads();
  for (int t = 0; t < TT; ++t) {
    if (j < DI) vcat[j] = bf2f(xp[t * DI + j]);
    __syncthreads();
    float a[8];
#pragma unroll
    for (int k = 0; k < 8; ++k) a[k] = bi_r[k];
#pragma unroll
    for (int r = 0; r < 8; ++r) {
      const u16* wr = Wi + ((size_t)(j + 256 * r)) * DI;
      float acc = a[r];
#pragma unroll
      for (int kk = 0; kk < DI; kk += 8) fma8(acc, *(const uint4*)(wr + kk), vcat + kk);
      a[r] = acc;
    }
#pragma unroll 1
    for (int kb = 0; kb < DH; kb += 64) {
      float hreg[64];
#pragma unroll
      for (int q = 0; q < 16; ++q)
        *(float4*)(hreg + 4 * q) = *(const float4*)(hprev + kb + 4 * q);
#pragma unroll
      for (int r = 0; r < 8; ++r) {
        const u16* wr = Wh + ((size_t)(j + 256 * r)) * DH + kb;
        float acc = a[r];
#pragma unroll
        for (int cc = 0; cc < 8; ++cc) fma8(acc, *(const uint4*)(wr + 8 * cc), hreg + 8 * cc);
        a[r] = acc;
      }
    }
    {
      const float cn0 = fmaf(c0, fsig(a[4] + 1.f), ftanh(a[0]) * fsig(a[2]));
      const float cn1 = fmaf(c1, fsig(a[5] + 1.f), ftanh(a[1]) * fsig(a[3]));
      c0 = cn0; c1 = cn1;
      vcat[DI + u0] = ftanh(cn0) * fsig(a[6]);
      vcat[DI + u1] = ftanh(cn1) * fsig(a[7]);
    }
    __syncthreads();
    {
      const int mm = j & (DB - 1), pp = j >> 7;
      const u16* br = bbW + (size_t)mm * KZ + pp * 288;
      const float* vs = vcat + pp * 288;
      float s0 = 0.f, s1 = 0.f, s2v = 0.f, s3 = 0.f;
#pragma unroll
      for (int kk = 0; kk < 288; kk += 32) {
        fma8(s0, *(const uint4*)(br + kk), vs + kk);
        fma8(s1, *(const uint4*)(br + kk + 8), vs + kk + 8);
        fma8(s2v, *(const uint4*)(br + kk + 16), vs + kk + 16);
        fma8(s3, *(const uint4*)(br + kk + 24), vs + kk + 24);
      }
      fpart[j] = (s0 + s1) + (s2v + s3);
    }
    __syncthreads();
    if (j < DB) Fb2[j] = 1.7159f * ftanh(0.666f * (b_bb + fpart[j] + fpart[j + DB]));
    __syncthreads();
    {
      float Fr[DB];
#pragma unroll
      for (int q = 0; q < 32; ++q) *(float4*)(Fr + 4 * q) = *(const float4*)(Fb2 + 4 * q);
      const u16* rp[8] = {
        f1W + (size_t)u0 * DB, f1W + (size_t)u1 * DB,
        f2W + (size_t)u0 * DB, f2W + (size_t)u1 * DB,
        taW + (size_t)u0 * DB, taW + (size_t)u1 * DB,
        tbW + (size_t)u0 * DB, tbW + (size_t)u1 * DB };
      float sacc[8] = { b_f1_0, b_f1_1, b_f2_0, b_f2_1, b_ta_0, b_ta_1, b_tb_0, b_tb_1 };
#pragma unroll
      for (int rr = 0; rr < 8; ++rr) {
        float acc = sacc[rr];
        const u16* r = rp[rr];
#pragma unroll
        for (int kk = 0; kk < DB; kk += 8) fma8(acc, *(const uint4*)(r + kk), Fr + kk);
        sacc[rr] = acc;
      }
      const float ti0 = fsig(sacc[4] + sacc[6]);
      const float ti1 = fsig(sacc[5] + sacc[7]);
      hprev[u0] = fmaf(ftanh(sacc[0]), 1.f - ti0, ti0 * ftanh(sacc[2]));
      hprev[u1] = fmaf(ftanh(sacc[1]), 1.f - ti1, ti1 * ftanh(sacc[3]));
    }
    __syncthreads();
    if (j < 128) {
      const int l = j & 63;
      float acc = 0.f;
#pragma unroll
      for (int q = 0; q < 8; ++q) acc = fmaf(hprev[q * 64 + l], hwr[q], acc);
#pragma unroll
      for (int off = 32; off > 0; off >>= 1) acc += __shfl_down(acc, off, 64);
      if (l == 0) out[((size_t)b * TT + t) * 2 + (j >> 6)] = acc + hbr;
    }
  }
  out[(size_t)NB * TT * 2 + (size_t)b * DH + u0] = hprev[u0];
  out[(size_t)NB * TT * 2 + (size_t)b * DH + u1] = hprev[u1];
}

extern "C" void kernel_launch(void* const* d_in, const int* in_sizes, int n_in,
                              void* d_out, int out_size, void* d_ws, size_t ws_size,
                              hipStream_t stream) {
  (void)in_sizes; (void)n_in; (void)out_size;

  if (ws_size >= WS_NEED) {
    char* ws = (char*)d_ws;
    int* flag = (int*)ws;
    detect_kernel<<<dim3(1), dim3(64), 0, stream>>>(
        (const u16*)d_in[0], (const u16*)d_in[1], (const u16*)d_in[3], flag);
    pwzx_kernel<<<dim3(8, 32), dim3(256), 0, stream>>>(d_in[1], flag, (u32*)(ws + O_WZX));
    qwz_kernel<<<dim3(2048), dim3(64), 0, stream>>>(d_in[3], flag,
                                                    (u32*)(ws + O_WZ8), (float*)(ws + O_SWZ));
    qbb_kernel<<<dim3(128), dim3(64), 0, stream>>>(d_in[4], flag,
                                                   (u32*)(ws + O_BB8), (float*)(ws + O_SBB));
    qff_kernel<<<dim3(512, 4), dim3(32), 0, stream>>>(d_in[6], d_in[8], d_in[10],
                                                      d_in[12], flag,
                                                      (u32*)(ws + O_FF8), (float*)(ws + O_SFF));
    psmall_kernel<<<dim3(1), dim3(1024), 0, stream>>>(
        d_in[2], d_in[7], d_in[9], d_in[11], d_in[13], d_in[5], d_in[14], d_in[15],
        flag, (float*)(ws + O_BIF), (float*)(ws + O_FFB), (float*)(ws + O_BBBF),
        (u32*)(ws + O_HWP), (float*)(ws + O_HBF));

    scan9<<<dim3(64), dim3(1024), 0, stream>>>(
        d_in[0], flag,
        (const u32*)(ws + O_WZX), (const u32*)(ws + O_WZ8), (const float*)(ws + O_SWZ),
        (const u32*)(ws + O_BB8), (const float*)(ws + O_SBB),
        (const u32*)(ws + O_FF8), (const float*)(ws + O_SFF),
        (const float*)(ws + O_BIF), (const float*)(ws + O_FFB),
        (const float*)(ws + O_BBBF), (const u32*)(ws + O_HWP),
        (const float*)(ws + O_HBF), (float*)d_out);
  } else {
    fb_scan<<<dim3(NB), dim3(256), 0, stream>>>(
        (const u16*)d_in[0],  (const u16*)d_in[1],  (const u16*)d_in[2],
        (const u16*)d_in[3],  (const u16*)d_in[4],  (const u16*)d_in[5],
        (const u16*)d_in[6],  (const u16*)d_in[7],  (const u16*)d_in[8],
        (const u16*)d_in[9],  (const u16*)d_in[10], (const u16*)d_in[11],
        (const u16*)d_in[12], (const u16*)d_in[13], (const u16*)d_in[14],
        (const u16*)d_in[15], (float*)d_out);
  }
}